// Round 4
// baseline (4873.865 us; speedup 1.0000x reference)
//
#include <hip/hip_runtime.h>

// ---------------- constants ----------------
#define NN    100000      // nodes per batch
#define NE    400000      // edges per batch
#define NG    4096        // graphs
#define LL    5
#define MPAD  100096      // 782*128
#define NCHUNK 98         // ceil(NN/1024)
#define TROWS 25088       // max rows per GEMM chunk (196*128)

typedef unsigned short u16;
typedef __attribute__((ext_vector_type(8))) _Float16 half8;
typedef __attribute__((ext_vector_type(4))) float float4v;

// bf16 decode/encode (for dtype probe + bf16-output fallback)
__device__ __forceinline__ float b2f(u16 u){
  union { float f; unsigned u; } c; c.u = ((unsigned)u)<<16; return c.f;
}
__device__ __forceinline__ u16 f2b(float f){
  union { float f; unsigned u; } c; c.f = f;
  unsigned x = c.u;
  return (u16)((x + 0x7fffu + ((x>>16)&1u)) >> 16);
}
// fp16 decode/encode (pipeline precision)
__device__ __forceinline__ float h2f(u16 u){
  union { u16 s; _Float16 h; } c; c.s = u; return (float)c.h;
}
__device__ __forceinline__ u16 f2h(float f){
  union { u16 s; _Float16 h; } c; c.h = (_Float16)f; return c.s;
}
__device__ __forceinline__ void g2l16(const u16* g, u16* l){
  __builtin_amdgcn_global_load_lds((const __attribute__((address_space(1))) void*)g,
                                   (__attribute__((address_space(3))) void*)l, 16, 0, 0);
}

// ---------------- dtype detection / normalization ----------------
// Decode first 4096 halves of a large random-valued param as bf16. If the
// underlying data is fp32, low halves are uniform mantissa bits -> huge
// exponents / NaN with certainty. flag=1 means "inputs are fp32".
__global__ __launch_bounds__(256) void detect_dtype(const u16* __restrict__ p, int* __restrict__ flag){
  int i = blockIdx.x*256 + threadIdx.x;   // grid: 16 blocks -> 4096 halves
  float v = b2f(p[i]);
  if (!(fabsf(v) <= 1e4f)) atomicOr(flag, 1);
}
// normalize a float param (fp32 or bf16 in memory) into fp16
__global__ __launch_bounds__(256) void cvt_param(const void* __restrict__ src, u16* __restrict__ dst,
                                                 int n, const int* __restrict__ flag){
  int i = blockIdx.x*256 + threadIdx.x;
  if (i >= n) return;
  float v = (*flag) ? ((const float*)src)[i] : b2f(((const u16*)src)[i]);
  dst[i] = f2h(v);
}

// ---------------- small utility kernels ----------------
__global__ __launch_bounds__(256) void zero32(unsigned* __restrict__ p, int n){
  int i = blockIdx.x*256 + threadIdx.x;
  if (i < n) p[i] = 0u;
}

// transpose+pad: dst[l][n][k] = src[l][k][n], zero outside (fp16 elements)
__global__ __launch_bounds__(256) void tpad(const u16* __restrict__ src, u16* __restrict__ dst,
                                            int L, int K, int N, int Kp, int Np){
  int idx = blockIdx.x*256 + threadIdx.x;
  if (idx >= L*Np*Kp) return;
  int l = idx/(Np*Kp); int r = idx - l*Np*Kp; int n = r/Kp; int k = r - n*Kp;
  dst[idx] = (n<N && k<K) ? src[(l*K + k)*N + n] : (u16)0;
}

// ecomb[l][c][0:320] = eemb1[l][c/3] + eemb2[l][c%3], cols>=300 zero. fp16.
__global__ __launch_bounds__(256) void ecomb_build(const u16* __restrict__ ee1, const u16* __restrict__ ee2,
                                                   u16* __restrict__ ec){
  int idx = blockIdx.x*256 + threadIdx.x;
  if (idx >= LL*18*160) return;
  int l = idx/(18*160); int r = idx - l*18*160; int c = r/160; int p = r - c*160;
  int a0 = c/3, a1 = c - a0*3;
  u16 o0=0,o1=0;
  if (p < 150){
    int d = 2*p;
    o0 = f2h(h2f(ee1[(l*6+a0)*300+d  ]) + h2f(ee2[(l*3+a1)*300+d  ]));
    o1 = f2h(h2f(ee1[(l*6+a0)*300+d+1]) + h2f(ee2[(l*3+a1)*300+d+1]));
  }
  ((ushort2*)ec)[idx] = make_ushort2(o0,o1);
}

// h[n][0:320] = atom_emb1[x[n,0]] + atom_emb2[x[n,1]]; pads zero (fp16)
__global__ __launch_bounds__(256) void node_init(const int* __restrict__ x, const u16* __restrict__ ae1,
                                                 const u16* __restrict__ ae2, u16* __restrict__ h){
  int idx = blockIdx.x*256 + threadIdx.x;
  if (idx >= MPAD*160) return;
  int n = idx/160, p = idx - n*160;
  u16 o0=0,o1=0;
  if (n < NN && p < 150){
    int a = x[2*n], ch = x[2*n+1];
    int d = 2*p;
    o0 = f2h(h2f(ae1[a*300+d  ]) + h2f(ae2[ch*300+d  ]));
    o1 = f2h(h2f(ae1[a*300+d+1]) + h2f(ae2[ch*300+d+1]));
  }
  ((ushort2*)h)[idx] = make_ushort2(o0,o1);
}

// ---------------- CSR build ----------------
__global__ __launch_bounds__(256) void hist(const int* __restrict__ ei, int* __restrict__ counts){
  int e = blockIdx.x*256 + threadIdx.x;
  if (e >= NE) return;
  atomicAdd(&counts[ei[NE + e]], 1);
}
__global__ __launch_bounds__(256) void scan_chunks(const int* __restrict__ counts, int* __restrict__ csums){
  __shared__ int sd[256];
  int base = blockIdx.x*1024;
  int s = 0;
  for (int i = threadIdx.x; i < 1024; i += 256){ int g = base+i; if (g < NN) s += counts[g]; }
  sd[threadIdx.x] = s; __syncthreads();
  for (int off=128; off>0; off>>=1){ if (threadIdx.x < off) sd[threadIdx.x] += sd[threadIdx.x+off]; __syncthreads(); }
  if (threadIdx.x == 0) csums[blockIdx.x] = sd[0];
}
__global__ __launch_bounds__(128) void scan_base(const int* __restrict__ csums, int* __restrict__ cbase,
                                                 int* __restrict__ offsets){
  __shared__ int sd[128];
  int tid = threadIdx.x;
  int v = (tid < NCHUNK) ? csums[tid] : 0;
  sd[tid] = v; __syncthreads();
  for (int off=1; off<128; off<<=1){
    int t = (tid >= off) ? sd[tid-off] : 0; __syncthreads();
    sd[tid] += t; __syncthreads();
  }
  if (tid < NCHUNK) cbase[tid] = sd[tid] - v;
  if (tid == 0) offsets[NN] = sd[NCHUNK-1];
}
__global__ __launch_bounds__(256) void scan_final(const int* __restrict__ counts, const int* __restrict__ cbase,
                                                  int* __restrict__ offsets){
  __shared__ int sd[256];
  int tid = threadIdx.x;
  int base = blockIdx.x*1024 + tid*4;
  int v0 = (base   < NN) ? counts[base  ] : 0;
  int v1 = (base+1 < NN) ? counts[base+1] : 0;
  int v2 = (base+2 < NN) ? counts[base+2] : 0;
  int v3 = (base+3 < NN) ? counts[base+3] : 0;
  int s = v0+v1+v2+v3;
  sd[tid] = s; __syncthreads();
  for (int off=1; off<256; off<<=1){
    int t = (tid >= off) ? sd[tid-off] : 0; __syncthreads();
    sd[tid] += t; __syncthreads();
  }
  int run = cbase[blockIdx.x] + sd[tid] - s;
  if (base   < NN){ offsets[base  ] = run; } run += v0;
  if (base+1 < NN){ offsets[base+1] = run; } run += v1;
  if (base+2 < NN){ offsets[base+2] = run; } run += v2;
  if (base+3 < NN){ offsets[base+3] = run; }
}
__global__ __launch_bounds__(256) void fill_perm(const int* __restrict__ ei, const int* __restrict__ offsets,
                                                 int* __restrict__ cursor, int* __restrict__ perm){
  int e = blockIdx.x*256 + threadIdx.x;
  if (e >= NE) return;
  int d = ei[NE + e];
  int pos = offsets[d] + atomicAdd(&cursor[d], 1);
  perm[pos] = e;
}

// ---------------- aggregation (wave per node) ----------------
__global__ __launch_bounds__(256) void aggregate(
    const u16* __restrict__ h, const u16* __restrict__ ecL,
    const int* __restrict__ offsets, const int* __restrict__ perm,
    const int* __restrict__ ei, const int* __restrict__ ea,
    u16* __restrict__ agg)
{
  int node = blockIdx.x*4 + (threadIdx.x>>6);
  int lane = threadIdx.x & 63;
  if (node >= MPAD) return;
  const ushort2* h2 = (const ushort2*)h;
  const ushort2* e2 = (const ushort2*)ecL;
  float ax[3], ay[3];
  int pbase = node*160;
  #pragma unroll
  for (int jp=0; jp<3; ++jp){
    int p = jp*64 + lane;
    float vx=0.f, vy=0.f;
    if (p < 160){
      ushort2 hv = h2[pbase+p];
      ushort2 ev = e2[12*160+p];     // self-loop: bond 4, dir 0 -> combo 12
      vx = h2f(hv.x)+h2f(ev.x); vy = h2f(hv.y)+h2f(ev.y);
    }
    ax[jp]=vx; ay[jp]=vy;
  }
  if (node < NN){
    int s = offsets[node], en = offsets[node+1];
    for (int i=s; i<en; ++i){
      int ed = perm[i];
      int src = ei[ed];
      int c = ea[2*ed]*3 + ea[2*ed+1];
      int hb = src*160, eb = c*160;
      #pragma unroll
      for (int jp=0; jp<3; ++jp){
        int p = jp*64 + lane;
        if (p < 160){
          ushort2 hv = h2[hb+p]; ushort2 ev = e2[eb+p];
          ax[jp] += h2f(hv.x)+h2f(ev.x); ay[jp] += h2f(hv.y)+h2f(ev.y);
        }
      }
    }
  }
  ushort2* a2 = (ushort2*)agg;
  #pragma unroll
  for (int jp=0; jp<3; ++jp){
    int p = jp*64 + lane;
    if (p < 160) a2[pbase+p] = make_ushort2(f2h(ax[jp]), f2h(ay[jp]));
  }
}

// ---------------- MFMA GEMM (fp16): C = A(row) * BT(row)^T, 128x128x32 tiles ----
// omode: 2 = fp16 out, 1 = bf16 out, 0 = fp32 out
__global__ __launch_bounds__(256) void gemm_nt(
    const u16* __restrict__ A, int lda,
    const u16* __restrict__ BT, int ldb,
    int Kp,
    const u16* __restrict__ bias, int Nreal,
    float scale, int dorelu, int omode, int Ncap,
    void* __restrict__ Cv, int ldc,
    float* __restrict__ colsum, float* __restrict__ colsumsq,
    int dostats, int statsLimit,
    const int* __restrict__ outmode)
{
  __shared__ __align__(16) u16 As[128*32];
  __shared__ __align__(16) u16 Bs[128*32];
  int tid = threadIdx.x;
  int wave = tid>>6, lane = tid&63;
  int wr = (wave>>1)&1, wc = wave&1;
  int m0 = blockIdx.x*128, n0 = blockIdx.y*128;
  int q = lane>>4, r = lane&15;
  int srow = tid>>2, scol = (tid&3)*8;
  const u16* Ag0 = A  + (long)(m0+srow)*lda + scol;
  const u16* Ag1 = A  + (long)(m0+64+srow)*lda + scol;
  const u16* Bg0 = BT + (long)(n0+srow)*ldb + scol;
  const u16* Bg1 = BT + (long)(n0+64+srow)*ldb + scol;
  u16* Asl0 = &As[tid*8];
  u16* Asl1 = &As[64*32 + tid*8];
  u16* Bsl0 = &Bs[tid*8];
  u16* Bsl1 = &Bs[64*32 + tid*8];
  float4v acc[4][4];
  #pragma unroll
  for (int i=0;i<4;i++)
    #pragma unroll
    for (int j=0;j<4;j++) acc[i][j] = (float4v){0.f,0.f,0.f,0.f};

  for (int k0=0; k0<Kp; k0+=32){
    g2l16(Ag0+k0, Asl0);
    g2l16(Ag1+k0, Asl1);
    g2l16(Bg0+k0, Bsl0);
    g2l16(Bg1+k0, Bsl1);
    __syncthreads();
    half8 af[4], bf[4];
    #pragma unroll
    for (int i=0;i<4;i++) af[i] = *(const half8*)&As[(wr*64+i*16+r)*32 + q*8];
    #pragma unroll
    for (int j=0;j<4;j++) bf[j] = *(const half8*)&Bs[(wc*64+j*16+r)*32 + q*8];
    #pragma unroll
    for (int i=0;i<4;i++)
      #pragma unroll
      for (int j=0;j<4;j++)
        acc[i][j] = __builtin_amdgcn_mfma_f32_16x16x32_f16(af[i], bf[j], acc[i][j], 0,0,0);
    __syncthreads();
  }

  int ob = omode;
  if (outmode) ob = (*outmode) ? 0 : 1;   // fp32 inputs -> fp32 logits, else bf16
  u16* Ch = (u16*)Cv; float* Cf = (float*)Cv;
  #pragma unroll
  for (int j=0;j<4;j++){
    int c = n0 + wc*64 + j*16 + r;
    float bv = (bias && c < Nreal) ? h2f(bias[c]) : 0.f;
    float s1 = 0.f, s2 = 0.f;
    #pragma unroll
    for (int i=0;i<4;i++){
      int rowb = m0 + wr*64 + i*16 + q*4;
      #pragma unroll
      for (int tt=0; tt<4; ++tt){
        float v = acc[i][j][tt] + bv;
        if (dorelu) v = fmaxf(v, 0.f);
        v *= scale;
        int gr = rowb + tt;
        if (c < Ncap){
          long o = (long)gr*ldc + c;
          if (ob == 2)      Ch[o] = f2h(v);
          else if (ob == 1) Ch[o] = f2b(v);
          else              Cf[o] = v;
        }
        if (dostats && gr < statsLimit){ s1 += v; s2 += v*v; }
      }
    }
    if (dostats){
      s1 += __shfl_xor(s1,16); s1 += __shfl_xor(s1,32);
      s2 += __shfl_xor(s2,16); s2 += __shfl_xor(s2,32);
      if (q == 0 && c < Ncap){ atomicAdd(&colsum[c], s1); atomicAdd(&colsumsq[c], s2); }
    }
  }
}

// ---------------- batchnorm ----------------
__global__ __launch_bounds__(320) void bn_finalize(const float* __restrict__ st, const u16* __restrict__ g,
                                                   const u16* __restrict__ b, float* __restrict__ sc,
                                                   float* __restrict__ sh){
  int c = threadIdx.x;
  if (c >= 300) return;
  float mu  = st[c] * (1.0f/NN);
  float var = st[384+c] * (1.0f/NN) - mu*mu;
  float inv = rsqrtf(var + 1e-5f);
  float gg = h2f(g[c]) * inv;
  sc[c] = gg; sh[c] = h2f(b[c]) - mu*gg;
}
__global__ __launch_bounds__(256) void bn_apply(const u16* __restrict__ z, const float* __restrict__ sc,
                                                const float* __restrict__ sh, u16* __restrict__ h, int dorelu){
  int idx = blockIdx.x*256 + threadIdx.x;
  if (idx >= NN*150) return;
  int n = idx/150, p = idx - n*150;
  ushort2 zz = ((const ushort2*)z)[n*160 + p];
  int d = 2*p;
  float v0 = h2f(zz.x)*sc[d  ] + sh[d  ];
  float v1 = h2f(zz.y)*sc[d+1] + sh[d+1];
  if (dorelu){ v0 = fmaxf(v0,0.f); v1 = fmaxf(v1,0.f); }
  ((ushort2*)h)[n*160 + p] = make_ushort2(f2h(v0), f2h(v1));
}

// ---------------- pooling / branch tail ----------------
__global__ __launch_bounds__(256) void graph_starts(const int* __restrict__ ids, int* __restrict__ starts){
  int i = blockIdx.x*256 + threadIdx.x;
  if (i >= NN) return;
  int b = ids[i];
  if (i == 0){ for (int g=0; g<=b; ++g) starts[g] = 0; }
  else { int p = ids[i-1]; for (int g=p+1; g<=b; ++g) starts[g] = i; }
  if (i == NN-1){ for (int g=b+1; g<=NG; ++g) starts[g] = NN; }
}
__global__ __launch_bounds__(256) void pool_kernel(const u16* __restrict__ h, const int* __restrict__ starts,
                                                   u16* __restrict__ pooled){
  int g = blockIdx.x*4 + (threadIdx.x>>6);
  int lane = threadIdx.x & 63;
  if (g >= NG) return;
  int s = starts[g], e = starts[g+1];
  int cnt = e - s; if (cnt < 1) cnt = 1;
  float inv = 1.0f/(float)cnt;
  float ax[3] = {0,0,0}, ay[3] = {0,0,0};
  const ushort2* h2 = (const ushort2*)h;
  for (int row=s; row<e; ++row){
    int base = row*160;
    #pragma unroll
    for (int jp=0; jp<3; ++jp){
      int p = jp*64 + lane;
      if (p < 160){ ushort2 v = h2[base+p]; ax[jp] += h2f(v.x); ay[jp] += h2f(v.y); }
    }
  }
  ushort2* o2 = (ushort2*)pooled;
  #pragma unroll
  for (int jp=0; jp<3; ++jp){
    int p = jp*64 + lane;
    if (p < 160) o2[g*160+p] = make_ushort2(f2h(ax[jp]*inv), f2h(ay[jp]*inv));
  }
}
__global__ __launch_bounds__(256) void gather_rows(const u16* __restrict__ h, const int* __restrict__ idxs,
                                                   u16* __restrict__ out){
  int idx = blockIdx.x*256 + threadIdx.x;
  if (idx >= NG*160) return;
  int g = idx/160, p = idx - g*160;
  ((ushort2*)out)[idx] = ((const ushort2*)h)[idxs[g]*160 + p];
}
__global__ __launch_bounds__(256) void add_norm(const float* __restrict__ vp, const float* __restrict__ vd,
                                                u16* __restrict__ f){
  int g = blockIdx.x*4 + (threadIdx.x>>6);
  int lane = threadIdx.x & 63;
  if (g >= NG) return;
  float vals[5]; float ss = 0.f;
  #pragma unroll
  for (int t=0; t<5; ++t){
    int d = lane + 64*t; float v = 0.f;
    if (d < 300) v = vp[g*320+d] + vd[g*320+d];
    vals[t] = v; ss += v*v;
  }
  #pragma unroll
  for (int off=32; off>0; off>>=1) ss += __shfl_xor(ss, off);
  float inv = rsqrtf(ss);
  #pragma unroll
  for (int t=0; t<5; ++t){
    int d = lane + 64*t;
    if (d < 320) f[g*320+d] = f2h(d < 300 ? vals[t]*inv : 0.f);
  }
}

// ---------------- host orchestration ----------------
extern "C" void kernel_launch(void* const* d_in, const int* in_sizes, int n_in,
                              void* d_out, int out_size, void* d_ws, size_t ws_size,
                              hipStream_t stream)
{
  const int* xin[2]  = {(const int*)d_in[0], (const int*)d_in[5]};
  const int* ei[2]   = {(const int*)d_in[1], (const int*)d_in[6]};
  const int* ea[2]   = {(const int*)d_in[2], (const int*)d_in[7]};
  const int* bid[2]  = {(const int*)d_in[3], (const int*)d_in[8]};
  const int* dang[2] = {(const int*)d_in[4], (const int*)d_in[9]};
  (void)in_sizes; (void)n_in; (void)out_size; (void)ws_size;

  char* w = (char*)d_ws;
  auto alloc = [&](size_t bytes)->char* {
    char* p = w; w += (bytes + 255) & ~(size_t)255; return p;
  };
  // big buffers (z aliases agg: safe under stream ordering)
  u16* hA   = (u16*)alloc((size_t)MPAD*320*2);   // 64.06 MB
  u16* agg  = (u16*)alloc((size_t)MPAD*320*2);   // 64.06 MB (also "z")
  u16* z    = agg;
  u16* t    = (u16*)alloc((size_t)TROWS*640*2);  // 32.11 MB
  // tail buffers carved from t's space (never live at the same time as t)
  char* tb = (char*)t;
  u16*   pooled = (u16*)(tb);
  u16*   hd     = (u16*)(tb + 2621440);
  u16*   ubuf   = (u16*)(tb + 5242880);
  float* vpb    = (float*)(tb + 8388608);
  float* vdb    = (float*)(tb + 13631488);
  // small buffers
  u16* ec   = (u16*)alloc((size_t)LL*18*320*2);
  u16* W1T  = (u16*)alloc((size_t)LL*640*320*2);
  u16* W2T  = (u16*)alloc((size_t)LL*384*640*2);
  u16* pW1T = (u16*)alloc((size_t)4*384*320*2);
  u16* pW2T = (u16*)alloc((size_t)4*384*384*2);
  int* counts = (int*)alloc((size_t)NN*4);
  int* cursor = (int*)alloc((size_t)NN*4);
  int* offs   = (int*)alloc((size_t)(NN+1)*4);
  int* perm   = (int*)alloc((size_t)NE*4);
  int* csums  = (int*)alloc(512);
  int* cbase  = (int*)alloc(512);
  float* stats = (float*)alloc(768*4);
  float* bnsc  = (float*)alloc(384*4);
  float* bnsh  = (float*)alloc(384*4);
  int* starts  = (int*)alloc((size_t)(NG+1)*4);
  u16* f0b     = (u16*)alloc((size_t)NG*320*2);
  u16* f1b     = (u16*)alloc((size_t)NG*320*2);
  int* dflag   = (int*)alloc(256);
  // fp16 param arena (normalized copies of the 14 float inputs)
  const int pcnt[14] = {36000, 900, 9000, 4500, 900000, 3000, 900000, 1500,
                        1500, 1500, 360000, 1200, 360000, 1200};
  u16* parena = (u16*)alloc((size_t)2580300*2 + 14*256);
  u16* pp[14];
  { size_t off = 0;
    for (int i=0;i<14;i++){ pp[i] = parena + off; off += (size_t)((pcnt[i]+127)&~127); } }
  u16* ae1 = pp[0];  u16* ae2 = pp[1];  u16* ee1 = pp[2];  u16* ee2 = pp[3];
  u16* W1  = pp[4];  u16* b1  = pp[5];  u16* W2  = pp[6];  u16* b2  = pp[7];
  u16* bng = pp[8];  u16* bnb = pp[9];  u16* pW1 = pp[10]; u16* pb1 = pp[11];
  u16* pW2 = pp[12]; u16* pb2 = pp[13];

  auto cdiv = [](long a, long b){ return (int)((a + b - 1)/b); };
  auto gemm = [&](const u16* A, int lda, const u16* BT, int ldb, int Kp,
                  const u16* bias, int Nreal, float scale, int relu, int omode, int Ncap,
                  void* C, int ldc, int gx, int gy,
                  float* cs, float* cq, int dostats, int slim, const int* om){
    gemm_nt<<<dim3(gx,gy), 256, 0, stream>>>(A,lda,BT,ldb,Kp,bias,Nreal,scale,relu,omode,Ncap,
                                             C,ldc,cs,cq,dostats,slim,om);
  };

  // ---- dtype probe on W1 (d_in[14], 900k random normals) + param normalization ----
  zero32<<<1,256,0,stream>>>((unsigned*)dflag, 1);
  detect_dtype<<<16,256,0,stream>>>((const u16*)d_in[14], dflag);
  for (int i=0;i<14;i++)
    cvt_param<<<cdiv(pcnt[i],256),256,0,stream>>>(d_in[10+i], pp[i], pcnt[i], dflag);

  // weight prep (every call; inputs re-pristine each call)
  tpad<<<cdiv((long)LL*640*320,256),256,0,stream>>>(W1,  W1T,  LL, 300, 600, 320, 640);
  tpad<<<cdiv((long)LL*384*640,256),256,0,stream>>>(W2,  W2T,  LL, 600, 300, 640, 384);
  tpad<<<cdiv((long)4*384*320,256),256,0,stream>>>(pW1, pW1T, 4,  300, 300, 320, 384);
  tpad<<<cdiv((long)4*384*384,256),256,0,stream>>>(pW2, pW2T, 4,  300, 300, 384, 384);
  ecomb_build<<<cdiv((long)LL*18*160,256),256,0,stream>>>(ee1, ee2, ec);

  const int cstart[5] = {0, 25088, 50176, 75264, 100096};

  for (int br=0; br<2; ++br){
    u16* fo = br ? f1b : f0b;
    node_init<<<cdiv((long)MPAD*160,256),256,0,stream>>>(xin[br], ae1, ae2, hA);
    // CSR by dst
    zero32<<<cdiv(NN,256),256,0,stream>>>((unsigned*)counts, NN);
    hist<<<cdiv(NE,256),256,0,stream>>>(ei[br], counts);
    scan_chunks<<<NCHUNK,256,0,stream>>>(counts, csums);
    scan_base<<<1,128,0,stream>>>(csums, cbase, offs);
    scan_final<<<NCHUNK,256,0,stream>>>(counts, cbase, offs);
    zero32<<<cdiv(NN,256),256,0,stream>>>((unsigned*)cursor, NN);
    fill_perm<<<cdiv(NE,256),256,0,stream>>>(ei[br], offs, cursor, perm);

    for (int l=0; l<LL; ++l){
      aggregate<<<MPAD/4,256,0,stream>>>(hA, ec + (size_t)l*18*320, offs, perm, ei[br], ea[br], agg);
      zero32<<<3,256,0,stream>>>((unsigned*)stats, 768);
      for (int ch=0; ch<4; ++ch){
        int rows = cstart[ch+1]-cstart[ch];
        int gx = rows/128;
        const u16* Ab = agg + (size_t)cstart[ch]*320;
        gemm(Ab, 320, W1T + (size_t)l*640*320, 320, 320,
             b1 + l*600, 600, 1.f, 1, 2, 640, t, 640, gx, 5, nullptr, nullptr, 0, 0, nullptr);
        gemm(t, 640, W2T + (size_t)l*384*640, 640, 640,
             b2 + l*300, 300, 1.f, 0, 2, 320, z + (size_t)cstart[ch]*320, 320, gx, 3,
             stats, stats+384, 1, NN - cstart[ch], nullptr);
      }
      bn_finalize<<<1,320,0,stream>>>(stats, bng + l*300, bnb + l*300, bnsc, bnsh);
      bn_apply<<<cdiv((long)NN*150,256),256,0,stream>>>(z, bnsc, bnsh, hA, (l < LL-1) ? 1 : 0);
    }

    graph_starts<<<cdiv(NN,256),256,0,stream>>>(bid[br], starts);
    pool_kernel<<<NG/4,256,0,stream>>>(hA, starts, pooled);
    gather_rows<<<cdiv((long)NG*160,256),256,0,stream>>>(hA, dang[br], hd);

    int pi = br, dpi = 2 + br;
    gemm(pooled, 320, pW1T + (size_t)pi*384*320, 320, 320,
         pb1 + pi*300, 300, 1.f, 1, 2, 384, ubuf, 384, NG/128, 3, nullptr, nullptr, 0, 0, nullptr);
    gemm(ubuf, 384, pW2T + (size_t)pi*384*384, 384, 384,
         pb2 + pi*300, 300, 1.f, 0, 0, 320, vpb, 320, NG/128, 3, nullptr, nullptr, 0, 0, nullptr);
    gemm(hd, 320, pW1T + (size_t)dpi*384*320, 320, 320,
         pb1 + dpi*300, 300, 1.f, 1, 2, 384, ubuf, 384, NG/128, 3, nullptr, nullptr, 0, 0, nullptr);
    gemm(ubuf, 384, pW2T + (size_t)dpi*384*384, 384, 384,
         pb2 + dpi*300, 300, 1.f, 0, 0, 320, vdb, 320, NG/128, 3, nullptr, nullptr, 0, 0, nullptr);
    add_norm<<<NG/4,256,0,stream>>>(vpb, vdb, fo);
  }

  // logits = (f0 @ f1^T) / 0.04  -> dtype per detected mode (fp32 here)
  gemm(f0b, 320, f1b, 320, 320, nullptr, 0, 25.0f, 0, 1, NG,
       d_out, NG, NG/128, NG/128, nullptr, nullptr, 0, 0, dflag);
}

// Round 5
// 4755.925 us; speedup vs baseline: 1.0248x; 1.0248x over previous
//
#include <hip/hip_runtime.h>

// ---------------- constants ----------------
#define NN    100000      // nodes per batch
#define NE    400000      // edges per batch
#define NG    4096        // graphs
#define LL    5
#define MPAD  100096      // 782*128
#define NCHUNK 98         // ceil(NN/1024)

typedef unsigned short u16;
typedef __attribute__((ext_vector_type(8))) _Float16 half8;
typedef __attribute__((ext_vector_type(4))) float float4v;

// bf16 decode/encode (for dtype probe + bf16-output fallback)
__device__ __forceinline__ float b2f(u16 u){
  union { float f; unsigned u; } c; c.u = ((unsigned)u)<<16; return c.f;
}
__device__ __forceinline__ u16 f2b(float f){
  union { float f; unsigned u; } c; c.f = f;
  unsigned x = c.u;
  return (u16)((x + 0x7fffu + ((x>>16)&1u)) >> 16);
}
// fp16 decode/encode (pipeline precision)
__device__ __forceinline__ float h2f(u16 u){
  union { u16 s; _Float16 h; } c; c.s = u; return (float)c.h;
}
__device__ __forceinline__ u16 f2h(float f){
  union { u16 s; _Float16 h; } c; c.h = (_Float16)f; return c.s;
}
__device__ __forceinline__ void g2l16(const u16* g, u16* l){
  __builtin_amdgcn_global_load_lds((const __attribute__((address_space(1))) void*)g,
                                   (__attribute__((address_space(3))) void*)l, 16, 0, 0);
}

// ---------------- dtype detection / normalization ----------------
__global__ __launch_bounds__(256) void detect_dtype(const u16* __restrict__ p, int* __restrict__ flag){
  int i = blockIdx.x*256 + threadIdx.x;   // 16 blocks -> 4096 halves
  float v = b2f(p[i]);
  if (!(fabsf(v) <= 1e4f)) atomicOr(flag, 1);
}
__global__ __launch_bounds__(256) void cvt_param(const void* __restrict__ src, u16* __restrict__ dst,
                                                 int n, const int* __restrict__ flag){
  int i = blockIdx.x*256 + threadIdx.x;
  if (i >= n) return;
  float v = (*flag) ? ((const float*)src)[i] : b2f(((const u16*)src)[i]);
  dst[i] = f2h(v);
}

// ---------------- small utility kernels ----------------
__global__ __launch_bounds__(256) void zero32(unsigned* __restrict__ p, int n){
  int i = blockIdx.x*256 + threadIdx.x;
  if (i < n) p[i] = 0u;
}

// transpose+pad: dst[l][n][k] = src[l][k][n], zero outside (fp16 elements)
__global__ __launch_bounds__(256) void tpad(const u16* __restrict__ src, u16* __restrict__ dst,
                                            int L, int K, int N, int Kp, int Np){
  int idx = blockIdx.x*256 + threadIdx.x;
  if (idx >= L*Np*Kp) return;
  int l = idx/(Np*Kp); int r = idx - l*Np*Kp; int n = r/Kp; int k = r - n*Kp;
  dst[idx] = (n<N && k<K) ? src[(l*K + k)*N + n] : (u16)0;
}

// ecomb[l][c][0:320] = eemb1[l][c/3] + eemb2[l][c%3], cols>=300 zero. fp16.
__global__ __launch_bounds__(256) void ecomb_build(const u16* __restrict__ ee1, const u16* __restrict__ ee2,
                                                   u16* __restrict__ ec){
  int idx = blockIdx.x*256 + threadIdx.x;
  if (idx >= LL*18*160) return;
  int l = idx/(18*160); int r = idx - l*18*160; int c = r/160; int p = r - c*160;
  int a0 = c/3, a1 = c - a0*3;
  u16 o0=0,o1=0;
  if (p < 150){
    int d = 2*p;
    o0 = f2h(h2f(ee1[(l*6+a0)*300+d  ]) + h2f(ee2[(l*3+a1)*300+d  ]));
    o1 = f2h(h2f(ee1[(l*6+a0)*300+d+1]) + h2f(ee2[(l*3+a1)*300+d+1]));
  }
  ((ushort2*)ec)[idx] = make_ushort2(o0,o1);
}

// h[n][0:320] = atom_emb1[x[n,0]] + atom_emb2[x[n,1]]; pads zero (fp16)
__global__ __launch_bounds__(256) void node_init(const int* __restrict__ x, const u16* __restrict__ ae1,
                                                 const u16* __restrict__ ae2, u16* __restrict__ h){
  int idx = blockIdx.x*256 + threadIdx.x;
  if (idx >= MPAD*160) return;
  int n = idx/160, p = idx - n*160;
  u16 o0=0,o1=0;
  if (n < NN && p < 150){
    int a = x[2*n], ch = x[2*n+1];
    int d = 2*p;
    o0 = f2h(h2f(ae1[a*300+d  ]) + h2f(ae2[ch*300+d  ]));
    o1 = f2h(h2f(ae1[a*300+d+1]) + h2f(ae2[ch*300+d+1]));
  }
  ((ushort2*)h)[idx] = make_ushort2(o0,o1);
}

// ---------------- CSR build ----------------
__global__ __launch_bounds__(256) void hist(const int* __restrict__ ei, int* __restrict__ counts){
  int e = blockIdx.x*256 + threadIdx.x;
  if (e >= NE) return;
  atomicAdd(&counts[ei[NE + e]], 1);
}
__global__ __launch_bounds__(256) void scan_chunks(const int* __restrict__ counts, int* __restrict__ csums){
  __shared__ int sd[256];
  int base = blockIdx.x*1024;
  int s = 0;
  for (int i = threadIdx.x; i < 1024; i += 256){ int g = base+i; if (g < NN) s += counts[g]; }
  sd[threadIdx.x] = s; __syncthreads();
  for (int off=128; off>0; off>>=1){ if (threadIdx.x < off) sd[threadIdx.x] += sd[threadIdx.x+off]; __syncthreads(); }
  if (threadIdx.x == 0) csums[blockIdx.x] = sd[0];
}
__global__ __launch_bounds__(128) void scan_base(const int* __restrict__ csums, int* __restrict__ cbase,
                                                 int* __restrict__ offsets){
  __shared__ int sd[128];
  int tid = threadIdx.x;
  int v = (tid < NCHUNK) ? csums[tid] : 0;
  sd[tid] = v; __syncthreads();
  for (int off=1; off<128; off<<=1){
    int t = (tid >= off) ? sd[tid-off] : 0; __syncthreads();
    sd[tid] += t; __syncthreads();
  }
  if (tid < NCHUNK) cbase[tid] = sd[tid] - v;
  if (tid == 0) offsets[NN] = sd[NCHUNK-1];
}
__global__ __launch_bounds__(256) void scan_final(const int* __restrict__ counts, const int* __restrict__ cbase,
                                                  int* __restrict__ offsets){
  __shared__ int sd[256];
  int tid = threadIdx.x;
  int base = blockIdx.x*1024 + tid*4;
  int v0 = (base   < NN) ? counts[base  ] : 0;
  int v1 = (base+1 < NN) ? counts[base+1] : 0;
  int v2 = (base+2 < NN) ? counts[base+2] : 0;
  int v3 = (base+3 < NN) ? counts[base+3] : 0;
  int s = v0+v1+v2+v3;
  sd[tid] = s; __syncthreads();
  for (int off=1; off<256; off<<=1){
    int t = (tid >= off) ? sd[tid-off] : 0; __syncthreads();
    sd[tid] += t; __syncthreads();
  }
  int run = cbase[blockIdx.x] + sd[tid] - s;
  if (base   < NN){ offsets[base  ] = run; } run += v0;
  if (base+1 < NN){ offsets[base+1] = run; } run += v1;
  if (base+2 < NN){ offsets[base+2] = run; } run += v2;
  if (base+3 < NN){ offsets[base+3] = run; }
}
// pack src*32+combo so aggregate needs ONE load per edge (no ei/ea indirection)
__global__ __launch_bounds__(256) void fill_perm(const int* __restrict__ ei, const int* __restrict__ ea,
                                                 const int* __restrict__ offsets,
                                                 int* __restrict__ cursor, int* __restrict__ pk){
  int e = blockIdx.x*256 + threadIdx.x;
  if (e >= NE) return;
  int d = ei[NE + e];
  int src = ei[e];
  int c = ea[2*e]*3 + ea[2*e+1];
  int pos = offsets[d] + atomicAdd(&cursor[d], 1);
  pk[pos] = src*32 + c;
}

// ---------------- aggregation (wave per node, ushort4 lanes, 2-edge unroll) ------
__global__ __launch_bounds__(256) void aggregate(
    const u16* __restrict__ h, const u16* __restrict__ ecL,
    const int* __restrict__ offsets, const int* __restrict__ pk,
    u16* __restrict__ agg)
{
  __shared__ u16 ecs[18*320];
  for (int i = threadIdx.x; i < 18*160; i += 256)
    ((ushort2*)ecs)[i] = ((const ushort2*)ecL)[i];
  __syncthreads();
  int node = blockIdx.x*4 + (threadIdx.x>>6);
  int lane = threadIdx.x & 63;
  bool tl = lane < 16;
  const ushort4* h4 = (const ushort4*)h;
  long base = (long)node*80;
  float m0[4], m1[4] = {0,0,0,0};
  // self: h + ec[12] (bond 4, dir 0)
  {
    ushort4 hv = h4[base + lane];
    ushort4 ev = ((const ushort4*)(ecs + 12*320))[lane];
    m0[0]=h2f(hv.x)+h2f(ev.x); m0[1]=h2f(hv.y)+h2f(ev.y);
    m0[2]=h2f(hv.z)+h2f(ev.z); m0[3]=h2f(hv.w)+h2f(ev.w);
    if (tl){
      ushort4 hv2 = h4[base + 64 + lane];
      ushort4 ev2 = ((const ushort4*)(ecs + 12*320))[64 + lane];
      m1[0]=h2f(hv2.x)+h2f(ev2.x); m1[1]=h2f(hv2.y)+h2f(ev2.y);
      m1[2]=h2f(hv2.z)+h2f(ev2.z); m1[3]=h2f(hv2.w)+h2f(ev2.w);
    }
  }
  if (node < NN){
    int s = offsets[node], en = offsets[node+1];
    int i = s;
    while (i + 1 < en){
      int p0 = pk[i], p1 = pk[i+1]; i += 2;
      int s0 = p0>>5, c0 = p0&31;
      int s1 = p1>>5, c1 = p1&31;
      ushort4 ha0 = h4[(long)s0*80 + lane];
      ushort4 ha1 = h4[(long)s1*80 + lane];
      ushort4 e0 = ((const ushort4*)(ecs + c0*320))[lane];
      ushort4 e1 = ((const ushort4*)(ecs + c1*320))[lane];
      m0[0] += h2f(ha0.x)+h2f(e0.x) + h2f(ha1.x)+h2f(e1.x);
      m0[1] += h2f(ha0.y)+h2f(e0.y) + h2f(ha1.y)+h2f(e1.y);
      m0[2] += h2f(ha0.z)+h2f(e0.z) + h2f(ha1.z)+h2f(e1.z);
      m0[3] += h2f(ha0.w)+h2f(e0.w) + h2f(ha1.w)+h2f(e1.w);
      if (tl){
        ushort4 hb0 = h4[(long)s0*80 + 64 + lane];
        ushort4 hb1 = h4[(long)s1*80 + 64 + lane];
        ushort4 f0 = ((const ushort4*)(ecs + c0*320))[64 + lane];
        ushort4 f1 = ((const ushort4*)(ecs + c1*320))[64 + lane];
        m1[0] += h2f(hb0.x)+h2f(f0.x) + h2f(hb1.x)+h2f(f1.x);
        m1[1] += h2f(hb0.y)+h2f(f0.y) + h2f(hb1.y)+h2f(f1.y);
        m1[2] += h2f(hb0.z)+h2f(f0.z) + h2f(hb1.z)+h2f(f1.z);
        m1[3] += h2f(hb0.w)+h2f(f0.w) + h2f(hb1.w)+h2f(f1.w);
      }
    }
    if (i < en){
      int p0 = pk[i];
      int s0 = p0>>5, c0 = p0&31;
      ushort4 ha0 = h4[(long)s0*80 + lane];
      ushort4 e0 = ((const ushort4*)(ecs + c0*320))[lane];
      m0[0] += h2f(ha0.x)+h2f(e0.x); m0[1] += h2f(ha0.y)+h2f(e0.y);
      m0[2] += h2f(ha0.z)+h2f(e0.z); m0[3] += h2f(ha0.w)+h2f(e0.w);
      if (tl){
        ushort4 hb0 = h4[(long)s0*80 + 64 + lane];
        ushort4 f0 = ((const ushort4*)(ecs + c0*320))[64 + lane];
        m1[0] += h2f(hb0.x)+h2f(f0.x); m1[1] += h2f(hb0.y)+h2f(f0.y);
        m1[2] += h2f(hb0.z)+h2f(f0.z); m1[3] += h2f(hb0.w)+h2f(f0.w);
      }
    }
  }
  ushort4* a4 = (ushort4*)agg;
  a4[base + lane] = make_ushort4(f2h(m0[0]), f2h(m0[1]), f2h(m0[2]), f2h(m0[3]));
  if (tl)
    a4[base + 64 + lane] = make_ushort4(f2h(m1[0]), f2h(m1[1]), f2h(m1[2]), f2h(m1[3]));
}

// ---------------- MFMA GEMM (fp16): C = A(row) * BT(row)^T, 128x128x32 tiles ----
// omode: 2 = fp16 out, 1 = bf16 out, 0 = fp32 out
__global__ __launch_bounds__(256) void gemm_nt(
    const u16* __restrict__ A, int lda,
    const u16* __restrict__ BT, int ldb,
    int Kp,
    const u16* __restrict__ bias, int Nreal,
    float scale, int dorelu, int omode, int Ncap,
    void* __restrict__ Cv, int ldc,
    float* __restrict__ colsum, float* __restrict__ colsumsq,
    int dostats, int statsLimit,
    const int* __restrict__ outmode)
{
  __shared__ __align__(16) u16 As[128*32];
  __shared__ __align__(16) u16 Bs[128*32];
  int tid = threadIdx.x;
  int wave = tid>>6, lane = tid&63;
  int wr = (wave>>1)&1, wc = wave&1;
  int m0 = blockIdx.x*128, n0 = blockIdx.y*128;
  int q = lane>>4, r = lane&15;
  int srow = tid>>2, scol = (tid&3)*8;
  const u16* Ag0 = A  + (long)(m0+srow)*lda + scol;
  const u16* Ag1 = A  + (long)(m0+64+srow)*lda + scol;
  const u16* Bg0 = BT + (long)(n0+srow)*ldb + scol;
  const u16* Bg1 = BT + (long)(n0+64+srow)*ldb + scol;
  u16* Asl0 = &As[tid*8];
  u16* Asl1 = &As[64*32 + tid*8];
  u16* Bsl0 = &Bs[tid*8];
  u16* Bsl1 = &Bs[64*32 + tid*8];
  float4v acc[4][4];
  #pragma unroll
  for (int i=0;i<4;i++)
    #pragma unroll
    for (int j=0;j<4;j++) acc[i][j] = (float4v){0.f,0.f,0.f,0.f};

  for (int k0=0; k0<Kp; k0+=32){
    g2l16(Ag0+k0, Asl0);
    g2l16(Ag1+k0, Asl1);
    g2l16(Bg0+k0, Bsl0);
    g2l16(Bg1+k0, Bsl1);
    __syncthreads();
    half8 af[4], bf[4];
    #pragma unroll
    for (int i=0;i<4;i++) af[i] = *(const half8*)&As[(wr*64+i*16+r)*32 + q*8];
    #pragma unroll
    for (int j=0;j<4;j++) bf[j] = *(const half8*)&Bs[(wc*64+j*16+r)*32 + q*8];
    #pragma unroll
    for (int i=0;i<4;i++)
      #pragma unroll
      for (int j=0;j<4;j++)
        acc[i][j] = __builtin_amdgcn_mfma_f32_16x16x32_f16(af[i], bf[j], acc[i][j], 0,0,0);
    __syncthreads();
  }

  int ob = omode;
  if (outmode) ob = (*outmode) ? 0 : 1;   // fp32 inputs -> fp32 logits, else bf16
  u16* Ch = (u16*)Cv; float* Cf = (float*)Cv;
  #pragma unroll
  for (int j=0;j<4;j++){
    int c = n0 + wc*64 + j*16 + r;
    float bv = (bias && c < Nreal) ? h2f(bias[c]) : 0.f;
    float s1 = 0.f, s2 = 0.f;
    #pragma unroll
    for (int i=0;i<4;i++){
      int rowb = m0 + wr*64 + i*16 + q*4;
      #pragma unroll
      for (int tt=0; tt<4; ++tt){
        float v = acc[i][j][tt] + bv;
        if (dorelu) v = fmaxf(v, 0.f);
        v *= scale;
        int gr = rowb + tt;
        if (c < Ncap){
          long o = (long)gr*ldc + c;
          if (ob == 2)      Ch[o] = f2h(v);
          else if (ob == 1) Ch[o] = f2b(v);
          else              Cf[o] = v;
        }
        if (dostats && gr < statsLimit){ s1 += v; s2 += v*v; }
      }
    }
    if (dostats){
      s1 += __shfl_xor(s1,16); s1 += __shfl_xor(s1,32);
      s2 += __shfl_xor(s2,16); s2 += __shfl_xor(s2,32);
      if (q == 0 && c < Ncap){ atomicAdd(&colsum[c], s1); atomicAdd(&colsumsq[c], s2); }
    }
  }
}

// ---------------- batchnorm ----------------
__global__ __launch_bounds__(320) void bn_finalize(const float* __restrict__ st, const u16* __restrict__ g,
                                                   const u16* __restrict__ b, float* __restrict__ sc,
                                                   float* __restrict__ sh){
  int c = threadIdx.x;
  if (c >= 300) return;
  float mu  = st[c] * (1.0f/NN);
  float var = st[384+c] * (1.0f/NN) - mu*mu;
  float inv = rsqrtf(var + 1e-5f);
  float gg = h2f(g[c]) * inv;
  sc[c] = gg; sh[c] = h2f(b[c]) - mu*gg;
}
__global__ __launch_bounds__(256) void bn_apply(const u16* __restrict__ z, const float* __restrict__ sc,
                                                const float* __restrict__ sh, u16* __restrict__ h, int dorelu){
  int idx = blockIdx.x*256 + threadIdx.x;
  if (idx >= NN*150) return;
  int n = idx/150, p = idx - n*150;
  ushort2 zz = ((const ushort2*)z)[n*160 + p];
  int d = 2*p;
  float v0 = h2f(zz.x)*sc[d  ] + sh[d  ];
  float v1 = h2f(zz.y)*sc[d+1] + sh[d+1];
  if (dorelu){ v0 = fmaxf(v0,0.f); v1 = fmaxf(v1,0.f); }
  ((ushort2*)h)[n*160 + p] = make_ushort2(f2h(v0), f2h(v1));
}

// ---------------- pooling / branch tail ----------------
__global__ __launch_bounds__(256) void graph_starts(const int* __restrict__ ids, int* __restrict__ starts){
  int i = blockIdx.x*256 + threadIdx.x;
  if (i >= NN) return;
  int b = ids[i];
  if (i == 0){ for (int g=0; g<=b; ++g) starts[g] = 0; }
  else { int p = ids[i-1]; for (int g=p+1; g<=b; ++g) starts[g] = i; }
  if (i == NN-1){ for (int g=b+1; g<=NG; ++g) starts[g] = NN; }
}
__global__ __launch_bounds__(256) void pool_kernel(const u16* __restrict__ h, const int* __restrict__ starts,
                                                   u16* __restrict__ pooled){
  int g = blockIdx.x*4 + (threadIdx.x>>6);
  int lane = threadIdx.x & 63;
  if (g >= NG) return;
  int s = starts[g], e = starts[g+1];
  int cnt = e - s; if (cnt < 1) cnt = 1;
  float inv = 1.0f/(float)cnt;
  float ax[3] = {0,0,0}, ay[3] = {0,0,0};
  const ushort2* h2 = (const ushort2*)h;
  for (int row=s; row<e; ++row){
    long base = (long)row*160;
    #pragma unroll
    for (int jp=0; jp<3; ++jp){
      int p = jp*64 + lane;
      if (p < 160){ ushort2 v = h2[base+p]; ax[jp] += h2f(v.x); ay[jp] += h2f(v.y); }
    }
  }
  ushort2* o2 = (ushort2*)pooled;
  #pragma unroll
  for (int jp=0; jp<3; ++jp){
    int p = jp*64 + lane;
    if (p < 160) o2[g*160+p] = make_ushort2(f2h(ax[jp]*inv), f2h(ay[jp]*inv));
  }
}
__global__ __launch_bounds__(256) void gather_rows(const u16* __restrict__ h, const int* __restrict__ idxs,
                                                   u16* __restrict__ out){
  int idx = blockIdx.x*256 + threadIdx.x;
  if (idx >= NG*160) return;
  int g = idx/160, p = idx - g*160;
  ((ushort2*)out)[idx] = ((const ushort2*)h)[(long)idxs[g]*160 + p];
}
__global__ __launch_bounds__(256) void add_norm(const float* __restrict__ vp, const float* __restrict__ vd,
                                                u16* __restrict__ f){
  int g = blockIdx.x*4 + (threadIdx.x>>6);
  int lane = threadIdx.x & 63;
  if (g >= NG) return;
  float vals[5]; float ss = 0.f;
  #pragma unroll
  for (int t=0; t<5; ++t){
    int d = lane + 64*t; float v = 0.f;
    if (d < 300) v = vp[g*320+d] + vd[g*320+d];
    vals[t] = v; ss += v*v;
  }
  #pragma unroll
  for (int off=32; off>0; off>>=1) ss += __shfl_xor(ss, off);
  float inv = rsqrtf(ss);
  #pragma unroll
  for (int t=0; t<5; ++t){
    int d = lane + 64*t;
    if (d < 320) f[g*320+d] = f2h(d < 300 ? vals[t]*inv : 0.f);
  }
}

// ---------------- host orchestration ----------------
extern "C" void kernel_launch(void* const* d_in, const int* in_sizes, int n_in,
                              void* d_out, int out_size, void* d_ws, size_t ws_size,
                              hipStream_t stream)
{
  const int* xin[2]  = {(const int*)d_in[0], (const int*)d_in[5]};
  const int* ei[2]   = {(const int*)d_in[1], (const int*)d_in[6]};
  const int* ea[2]   = {(const int*)d_in[2], (const int*)d_in[7]};
  const int* bid[2]  = {(const int*)d_in[3], (const int*)d_in[8]};
  const int* dang[2] = {(const int*)d_in[4], (const int*)d_in[9]};
  (void)in_sizes; (void)n_in; (void)out_size;

  // 2 chunks (t=64MB) if workspace allows, else 4 chunks (t=32MB)
  bool big = ws_size >= (size_t)226*1024*1024;
  int nch = big ? 2 : 4;
  const int cs2[3] = {0, 50048, 100096};
  const int cs4[5] = {0, 25088, 50176, 75264, 100096};
  const int* cstart = big ? cs2 : cs4;
  size_t tbytes = big ? (size_t)50048*640*2 : (size_t)25088*640*2;

  char* w = (char*)d_ws;
  auto alloc = [&](size_t bytes)->char* {
    char* p = w; w += (bytes + 255) & ~(size_t)255; return p;
  };
  // big buffers (z aliases agg: safe under stream ordering)
  u16* hA   = (u16*)alloc((size_t)MPAD*320*2);   // 64.06 MB
  u16* agg  = (u16*)alloc((size_t)MPAD*320*2);   // 64.06 MB (also "z")
  u16* z    = agg;
  u16* t    = (u16*)alloc(tbytes);
  // tail buffers carved from t's space (never live at the same time as t)
  char* tb = (char*)t;
  u16*   pooled = (u16*)(tb);
  u16*   hd     = (u16*)(tb + 2621440);
  u16*   ubuf   = (u16*)(tb + 5242880);
  float* vpb    = (float*)(tb + 8388608);
  float* vdb    = (float*)(tb + 13631488);
  // small buffers
  u16* ec   = (u16*)alloc((size_t)LL*18*320*2);
  u16* W1T  = (u16*)alloc((size_t)LL*640*320*2);
  u16* W2T  = (u16*)alloc((size_t)LL*384*640*2);
  u16* pW1T = (u16*)alloc((size_t)4*384*320*2);
  u16* pW2T = (u16*)alloc((size_t)4*384*384*2);
  int* counts = (int*)alloc((size_t)NN*4);
  int* cursor = (int*)alloc((size_t)NN*4);
  int* offs   = (int*)alloc((size_t)(NN+1)*4);
  int* perm   = (int*)alloc((size_t)NE*4);
  int* csums  = (int*)alloc(512);
  int* cbase  = (int*)alloc(512);
  float* stats = (float*)alloc(768*4);
  float* bnsc  = (float*)alloc(384*4);
  float* bnsh  = (float*)alloc(384*4);
  int* starts  = (int*)alloc((size_t)(NG+1)*4);
  u16* f0b     = (u16*)alloc((size_t)NG*320*2);
  u16* f1b     = (u16*)alloc((size_t)NG*320*2);
  int* dflag   = (int*)alloc(256);
  // fp16 param arena (normalized copies of the 14 float inputs)
  const int pcnt[14] = {36000, 900, 9000, 4500, 900000, 3000, 900000, 1500,
                        1500, 1500, 360000, 1200, 360000, 1200};
  u16* parena = (u16*)alloc((size_t)2580300*2 + 14*256);
  u16* pp[14];
  { size_t off = 0;
    for (int i=0;i<14;i++){ pp[i] = parena + off; off += (size_t)((pcnt[i]+127)&~127); } }
  u16* ae1 = pp[0];  u16* ae2 = pp[1];  u16* ee1 = pp[2];  u16* ee2 = pp[3];
  u16* W1  = pp[4];  u16* b1  = pp[5];  u16* W2  = pp[6];  u16* b2  = pp[7];
  u16* bng = pp[8];  u16* bnb = pp[9];  u16* pW1 = pp[10]; u16* pb1 = pp[11];
  u16* pW2 = pp[12]; u16* pb2 = pp[13];

  auto cdiv = [](long a, long b){ return (int)((a + b - 1)/b); };
  auto gemm = [&](const u16* A, int lda, const u16* BT, int ldb, int Kp,
                  const u16* bias, int Nreal, float scale, int relu, int omode, int Ncap,
                  void* C, int ldc, int gx, int gy,
                  float* cs, float* cq, int dostats, int slim, const int* om){
    gemm_nt<<<dim3(gx,gy), 256, 0, stream>>>(A,lda,BT,ldb,Kp,bias,Nreal,scale,relu,omode,Ncap,
                                             C,ldc,cs,cq,dostats,slim,om);
  };

  // ---- dtype probe on W1 (d_in[14], 900k random normals) + param normalization ----
  zero32<<<1,256,0,stream>>>((unsigned*)dflag, 1);
  detect_dtype<<<16,256,0,stream>>>((const u16*)d_in[14], dflag);
  for (int i=0;i<14;i++)
    cvt_param<<<cdiv(pcnt[i],256),256,0,stream>>>(d_in[10+i], pp[i], pcnt[i], dflag);

  // weight prep (every call; inputs re-pristine each call)
  tpad<<<cdiv((long)LL*640*320,256),256,0,stream>>>(W1,  W1T,  LL, 300, 600, 320, 640);
  tpad<<<cdiv((long)LL*384*640,256),256,0,stream>>>(W2,  W2T,  LL, 600, 300, 640, 384);
  tpad<<<cdiv((long)4*384*320,256),256,0,stream>>>(pW1, pW1T, 4,  300, 300, 320, 384);
  tpad<<<cdiv((long)4*384*384,256),256,0,stream>>>(pW2, pW2T, 4,  300, 300, 384, 384);
  ecomb_build<<<cdiv((long)LL*18*160,256),256,0,stream>>>(ee1, ee2, ec);

  for (int br=0; br<2; ++br){
    u16* fo = br ? f1b : f0b;
    node_init<<<cdiv((long)MPAD*160,256),256,0,stream>>>(xin[br], ae1, ae2, hA);
    // CSR by dst (perm stores packed src*32+combo)
    zero32<<<cdiv(NN,256),256,0,stream>>>((unsigned*)counts, NN);
    hist<<<cdiv(NE,256),256,0,stream>>>(ei[br], counts);
    scan_chunks<<<NCHUNK,256,0,stream>>>(counts, csums);
    scan_base<<<1,128,0,stream>>>(csums, cbase, offs);
    scan_final<<<NCHUNK,256,0,stream>>>(counts, cbase, offs);
    zero32<<<cdiv(NN,256),256,0,stream>>>((unsigned*)cursor, NN);
    fill_perm<<<cdiv(NE,256),256,0,stream>>>(ei[br], ea[br], offs, cursor, perm);

    for (int l=0; l<LL; ++l){
      aggregate<<<MPAD/4,256,0,stream>>>(hA, ec + (size_t)l*18*320, offs, perm, agg);
      zero32<<<3,256,0,stream>>>((unsigned*)stats, 768);
      for (int ch=0; ch<nch; ++ch){
        int rows = cstart[ch+1]-cstart[ch];
        int gx = rows/128;
        const u16* Ab = agg + (size_t)cstart[ch]*320;
        gemm(Ab, 320, W1T + (size_t)l*640*320, 320, 320,
             b1 + l*600, 600, 1.f, 1, 2, 640, t, 640, gx, 5, nullptr, nullptr, 0, 0, nullptr);
        gemm(t, 640, W2T + (size_t)l*384*640, 640, 640,
             b2 + l*300, 300, 1.f, 0, 2, 320, z + (size_t)cstart[ch]*320, 320, gx, 3,
             stats, stats+384, 1, NN - cstart[ch], nullptr);
      }
      bn_finalize<<<1,320,0,stream>>>(stats, bng + l*300, bnb + l*300, bnsc, bnsh);
      bn_apply<<<cdiv((long)NN*150,256),256,0,stream>>>(z, bnsc, bnsh, hA, (l < LL-1) ? 1 : 0);
    }

    graph_starts<<<cdiv(NN,256),256,0,stream>>>(bid[br], starts);
    pool_kernel<<<NG/4,256,0,stream>>>(hA, starts, pooled);
    gather_rows<<<cdiv((long)NG*160,256),256,0,stream>>>(hA, dang[br], hd);

    int pi = br, dpi = 2 + br;
    gemm(pooled, 320, pW1T + (size_t)pi*384*320, 320, 320,
         pb1 + pi*300, 300, 1.f, 1, 2, 384, ubuf, 384, NG/128, 3, nullptr, nullptr, 0, 0, nullptr);
    gemm(ubuf, 384, pW2T + (size_t)pi*384*384, 384, 384,
         pb2 + pi*300, 300, 1.f, 0, 0, 320, vpb, 320, NG/128, 3, nullptr, nullptr, 0, 0, nullptr);
    gemm(hd, 320, pW1T + (size_t)dpi*384*320, 320, 320,
         pb1 + dpi*300, 300, 1.f, 1, 2, 384, ubuf, 384, NG/128, 3, nullptr, nullptr, 0, 0, nullptr);
    gemm(ubuf, 384, pW2T + (size_t)dpi*384*384, 384, 384,
         pb2 + dpi*300, 300, 1.f, 0, 0, 320, vdb, 320, NG/128, 3, nullptr, nullptr, 0, 0, nullptr);
    add_norm<<<NG/4,256,0,stream>>>(vpb, vdb, fo);
  }

  // logits = (f0 @ f1^T) / 0.04  -> dtype per detected mode (fp32 here)
  gemm(f0b, 320, f1b, 320, 320, nullptr, 0, 25.0f, 0, 1, NG,
       d_out, NG, NG/128, NG/128, nullptr, nullptr, 0, 0, dflag);
}

// Round 6
// 4013.344 us; speedup vs baseline: 1.2144x; 1.1850x over previous
//
#include <hip/hip_runtime.h>

// ---------------- constants ----------------
#define NN    100000      // nodes per batch
#define NE    400000      // edges per batch
#define NG    4096        // graphs
#define LL    5
#define MPAD  100096      // 782*128
#define NCHUNK 98         // ceil(NN/1024)

typedef unsigned short u16;
typedef __attribute__((ext_vector_type(8))) _Float16 half8;
typedef __attribute__((ext_vector_type(4))) float float4v;

// bf16 decode/encode (for dtype probe + bf16-output fallback)
__device__ __forceinline__ float b2f(u16 u){
  union { float f; unsigned u; } c; c.u = ((unsigned)u)<<16; return c.f;
}
__device__ __forceinline__ u16 f2b(float f){
  union { float f; unsigned u; } c; c.f = f;
  unsigned x = c.u;
  return (u16)((x + 0x7fffu + ((x>>16)&1u)) >> 16);
}
// fp16 decode/encode (pipeline precision)
__device__ __forceinline__ float h2f(u16 u){
  union { u16 s; _Float16 h; } c; c.s = u; return (float)c.h;
}
__device__ __forceinline__ u16 f2h(float f){
  union { u16 s; _Float16 h; } c; c.h = (_Float16)f; return c.s;
}
__device__ __forceinline__ void g2l16(const u16* g, u16* l){
  __builtin_amdgcn_global_load_lds((const __attribute__((address_space(1))) void*)g,
                                   (__attribute__((address_space(3))) void*)l, 16, 0, 0);
}

// ---------------- dtype detection / normalization ----------------
__global__ __launch_bounds__(256) void detect_dtype(const u16* __restrict__ p, int* __restrict__ flag){
  int i = blockIdx.x*256 + threadIdx.x;   // 16 blocks -> 4096 halves
  float v = b2f(p[i]);
  if (!(fabsf(v) <= 1e4f)) atomicOr(flag, 1);
}
__global__ __launch_bounds__(256) void cvt_param(const void* __restrict__ src, u16* __restrict__ dst,
                                                 int n, const int* __restrict__ flag){
  int i = blockIdx.x*256 + threadIdx.x;
  if (i >= n) return;
  float v = (*flag) ? ((const float*)src)[i] : b2f(((const u16*)src)[i]);
  dst[i] = f2h(v);
}

// ---------------- small utility kernels ----------------
__global__ __launch_bounds__(256) void zero32(unsigned* __restrict__ p, int n){
  int i = blockIdx.x*256 + threadIdx.x;
  if (i < n) p[i] = 0u;
}

// transpose+pad: dst[l][n][k] = src[l][k][n], zero outside (fp16 elements)
__global__ __launch_bounds__(256) void tpad(const u16* __restrict__ src, u16* __restrict__ dst,
                                            int L, int K, int N, int Kp, int Np){
  int idx = blockIdx.x*256 + threadIdx.x;
  if (idx >= L*Np*Kp) return;
  int l = idx/(Np*Kp); int r = idx - l*Np*Kp; int n = r/Kp; int k = r - n*Kp;
  dst[idx] = (n<N && k<K) ? src[(l*K + k)*N + n] : (u16)0;
}

// ecomb[l][c][0:320] = eemb1[l][c/3] + eemb2[l][c%3], cols>=300 zero. fp16.
__global__ __launch_bounds__(256) void ecomb_build(const u16* __restrict__ ee1, const u16* __restrict__ ee2,
                                                   u16* __restrict__ ec){
  int idx = blockIdx.x*256 + threadIdx.x;
  if (idx >= LL*18*160) return;
  int l = idx/(18*160); int r = idx - l*18*160; int c = r/160; int p = r - c*160;
  int a0 = c/3, a1 = c - a0*3;
  u16 o0=0,o1=0;
  if (p < 150){
    int d = 2*p;
    o0 = f2h(h2f(ee1[(l*6+a0)*300+d  ]) + h2f(ee2[(l*3+a1)*300+d  ]));
    o1 = f2h(h2f(ee1[(l*6+a0)*300+d+1]) + h2f(ee2[(l*3+a1)*300+d+1]));
  }
  ((ushort2*)ec)[idx] = make_ushort2(o0,o1);
}

// h[n][0:320] = atom_emb1[x[n,0]] + atom_emb2[x[n,1]]; pads zero (fp16)
__global__ __launch_bounds__(256) void node_init(const int* __restrict__ x, const u16* __restrict__ ae1,
                                                 const u16* __restrict__ ae2, u16* __restrict__ h){
  int idx = blockIdx.x*256 + threadIdx.x;
  if (idx >= MPAD*160) return;
  int n = idx/160, p = idx - n*160;
  u16 o0=0,o1=0;
  if (n < NN && p < 150){
    int a = x[2*n], ch = x[2*n+1];
    int d = 2*p;
    o0 = f2h(h2f(ae1[a*300+d  ]) + h2f(ae2[ch*300+d  ]));
    o1 = f2h(h2f(ae1[a*300+d+1]) + h2f(ae2[ch*300+d+1]));
  }
  ((ushort2*)h)[idx] = make_ushort2(o0,o1);
}

// ---------------- CSR build ----------------
__global__ __launch_bounds__(256) void hist(const int* __restrict__ ei, int* __restrict__ counts){
  int e = blockIdx.x*256 + threadIdx.x;
  if (e >= NE) return;
  atomicAdd(&counts[ei[NE + e]], 1);
}
__global__ __launch_bounds__(256) void scan_chunks(const int* __restrict__ counts, int* __restrict__ csums){
  __shared__ int sd[256];
  int base = blockIdx.x*1024;
  int s = 0;
  for (int i = threadIdx.x; i < 1024; i += 256){ int g = base+i; if (g < NN) s += counts[g]; }
  sd[threadIdx.x] = s; __syncthreads();
  for (int off=128; off>0; off>>=1){ if (threadIdx.x < off) sd[threadIdx.x] += sd[threadIdx.x+off]; __syncthreads(); }
  if (threadIdx.x == 0) csums[blockIdx.x] = sd[0];
}
__global__ __launch_bounds__(128) void scan_base(const int* __restrict__ csums, int* __restrict__ cbase,
                                                 int* __restrict__ offsets){
  __shared__ int sd[128];
  int tid = threadIdx.x;
  int v = (tid < NCHUNK) ? csums[tid] : 0;
  sd[tid] = v; __syncthreads();
  for (int off=1; off<128; off<<=1){
    int t = (tid >= off) ? sd[tid-off] : 0; __syncthreads();
    sd[tid] += t; __syncthreads();
  }
  if (tid < NCHUNK) cbase[tid] = sd[tid] - v;
  if (tid == 0) offsets[NN] = sd[NCHUNK-1];
}
__global__ __launch_bounds__(256) void scan_final(const int* __restrict__ counts, const int* __restrict__ cbase,
                                                  int* __restrict__ offsets){
  __shared__ int sd[256];
  int tid = threadIdx.x;
  int base = blockIdx.x*1024 + tid*4;
  int v0 = (base   < NN) ? counts[base  ] : 0;
  int v1 = (base+1 < NN) ? counts[base+1] : 0;
  int v2 = (base+2 < NN) ? counts[base+2] : 0;
  int v3 = (base+3 < NN) ? counts[base+3] : 0;
  int s = v0+v1+v2+v3;
  sd[tid] = s; __syncthreads();
  for (int off=1; off<256; off<<=1){
    int t = (tid >= off) ? sd[tid-off] : 0; __syncthreads();
    sd[tid] += t; __syncthreads();
  }
  int run = cbase[blockIdx.x] + sd[tid] - s;
  if (base   < NN){ offsets[base  ] = run; } run += v0;
  if (base+1 < NN){ offsets[base+1] = run; } run += v1;
  if (base+2 < NN){ offsets[base+2] = run; } run += v2;
  if (base+3 < NN){ offsets[base+3] = run; }
}
// pack src*32+combo so aggregate needs ONE load per edge
__global__ __launch_bounds__(256) void fill_perm(const int* __restrict__ ei, const int* __restrict__ ea,
                                                 const int* __restrict__ offsets,
                                                 int* __restrict__ cursor, int* __restrict__ pk){
  int e = blockIdx.x*256 + threadIdx.x;
  if (e >= NE) return;
  int d = ei[NE + e];
  int src = ei[e];
  int c = ea[2*e]*3 + ea[2*e+1];
  int pos = offsets[d] + atomicAdd(&cursor[d], 1);
  pk[pos] = src*32 + c;
}

// ---------------- aggregation (wave per node, ushort4 lanes, 2-edge unroll) ------
__global__ __launch_bounds__(256) void aggregate(
    const u16* __restrict__ h, const u16* __restrict__ ecL,
    const int* __restrict__ offsets, const int* __restrict__ pk,
    u16* __restrict__ agg)
{
  __shared__ u16 ecs[18*320];
  for (int i = threadIdx.x; i < 18*160; i += 256)
    ((ushort2*)ecs)[i] = ((const ushort2*)ecL)[i];
  __syncthreads();
  int node = blockIdx.x*4 + (threadIdx.x>>6);
  int lane = threadIdx.x & 63;
  bool tl = lane < 16;
  const ushort4* h4 = (const ushort4*)h;
  long base = (long)node*80;
  float m0[4], m1[4] = {0,0,0,0};
  {
    ushort4 hv = h4[base + lane];
    ushort4 ev = ((const ushort4*)(ecs + 12*320))[lane];
    m0[0]=h2f(hv.x)+h2f(ev.x); m0[1]=h2f(hv.y)+h2f(ev.y);
    m0[2]=h2f(hv.z)+h2f(ev.z); m0[3]=h2f(hv.w)+h2f(ev.w);
    if (tl){
      ushort4 hv2 = h4[base + 64 + lane];
      ushort4 ev2 = ((const ushort4*)(ecs + 12*320))[64 + lane];
      m1[0]=h2f(hv2.x)+h2f(ev2.x); m1[1]=h2f(hv2.y)+h2f(ev2.y);
      m1[2]=h2f(hv2.z)+h2f(ev2.z); m1[3]=h2f(hv2.w)+h2f(ev2.w);
    }
  }
  if (node < NN){
    int s = offsets[node], en = offsets[node+1];
    int i = s;
    while (i + 1 < en){
      int p0 = pk[i], p1 = pk[i+1]; i += 2;
      int s0 = p0>>5, c0 = p0&31;
      int s1 = p1>>5, c1 = p1&31;
      ushort4 ha0 = h4[(long)s0*80 + lane];
      ushort4 ha1 = h4[(long)s1*80 + lane];
      ushort4 e0 = ((const ushort4*)(ecs + c0*320))[lane];
      ushort4 e1 = ((const ushort4*)(ecs + c1*320))[lane];
      m0[0] += h2f(ha0.x)+h2f(e0.x) + h2f(ha1.x)+h2f(e1.x);
      m0[1] += h2f(ha0.y)+h2f(e0.y) + h2f(ha1.y)+h2f(e1.y);
      m0[2] += h2f(ha0.z)+h2f(e0.z) + h2f(ha1.z)+h2f(e1.z);
      m0[3] += h2f(ha0.w)+h2f(e0.w) + h2f(ha1.w)+h2f(e1.w);
      if (tl){
        ushort4 hb0 = h4[(long)s0*80 + 64 + lane];
        ushort4 hb1 = h4[(long)s1*80 + 64 + lane];
        ushort4 f0 = ((const ushort4*)(ecs + c0*320))[64 + lane];
        ushort4 f1 = ((const ushort4*)(ecs + c1*320))[64 + lane];
        m1[0] += h2f(hb0.x)+h2f(f0.x) + h2f(hb1.x)+h2f(f1.x);
        m1[1] += h2f(hb0.y)+h2f(f0.y) + h2f(hb1.y)+h2f(f1.y);
        m1[2] += h2f(hb0.z)+h2f(f0.z) + h2f(hb1.z)+h2f(f1.z);
        m1[3] += h2f(hb0.w)+h2f(f0.w) + h2f(hb1.w)+h2f(f1.w);
      }
    }
    if (i < en){
      int p0 = pk[i];
      int s0 = p0>>5, c0 = p0&31;
      ushort4 ha0 = h4[(long)s0*80 + lane];
      ushort4 e0 = ((const ushort4*)(ecs + c0*320))[lane];
      m0[0] += h2f(ha0.x)+h2f(e0.x); m0[1] += h2f(ha0.y)+h2f(e0.y);
      m0[2] += h2f(ha0.z)+h2f(e0.z); m0[3] += h2f(ha0.w)+h2f(e0.w);
      if (tl){
        ushort4 hb0 = h4[(long)s0*80 + 64 + lane];
        ushort4 f0 = ((const ushort4*)(ecs + c0*320))[64 + lane];
        m1[0] += h2f(hb0.x)+h2f(f0.x); m1[1] += h2f(hb0.y)+h2f(f0.y);
        m1[2] += h2f(hb0.z)+h2f(f0.z); m1[3] += h2f(hb0.w)+h2f(f0.w);
      }
    }
  }
  ushort4* a4 = (ushort4*)agg;
  a4[base + lane] = make_ushort4(f2h(m0[0]), f2h(m0[1]), f2h(m0[2]), f2h(m0[3]));
  if (tl)
    a4[base + 64 + lane] = make_ushort4(f2h(m1[0]), f2h(m1[1]), f2h(m1[2]), f2h(m1[3]));
}

// ---------------- FUSED GIN MLP: z = relu(A*W1+b1)*W2+b2 + BN stats -------------
// block = 128 rows, 512 threads (8 waves). A tile in registers (read once).
// u (hidden, 640) processed in 10 tiles of 64 cols, round-trip through LDS.
// W1/W2 tiles staged via global_load_lds into shared 48KB region (aliased).
// LDS: uS [2][128][32] = 16KB @0, Ws 48KB @8192(u16). Total exactly 64KB.
__global__ __launch_bounds__(512, 2) void gin_mlp(
    const u16* __restrict__ A,        // [MPAD][320]
    const u16* __restrict__ W1Tl,     // [640][320]
    const u16* __restrict__ b1l,      // [600]
    const u16* __restrict__ W2Tl,     // [384][640]
    const u16* __restrict__ b2l,      // [300]
    u16* __restrict__ Z,              // [MPAD][320]
    float* __restrict__ colsum, float* __restrict__ colsumsq)
{
  __shared__ __align__(16) u16 lds[32768];   // 64 KB
  u16* uS = lds;           // [kc2][128][32]
  u16* Ws = lds + 8192;    // W1 tile [10][64][32] (20480) or W2 tile [2][384][32] (24576)
  int tid = threadIdx.x;
  int wave = tid>>6, lane = tid&63;
  int q = lane>>4, r = lane&15;
  int wr = wave>>2, wc = wave&3;      // z: rows wr*64, cols wc*96
  int m0 = blockIdx.x*128;

  // A rows into registers: lane covers row (wave*16+r), k = kc*32 + q*8
  half8 aReg[10];
  const u16* Arow = A + (long)(m0 + wave*16 + r)*320 + q*8;
  #pragma unroll
  for (int kc=0; kc<10; ++kc) aReg[kc] = *(const half8*)(Arow + kc*32);

  float4v zacc[4][6];
  #pragma unroll
  for (int i=0;i<4;i++)
    #pragma unroll
    for (int j=0;j<6;j++) zacc[i][j] = (float4v){0.f,0.f,0.f,0.f};

  for (int t1=0; t1<10; ++t1){
    int n1_0 = t1*64;
    __syncthreads();   // prior z-phase done reading uS/Ws
    // stage W1 tile: rows n1_0..+63 of W1T, all K -> [kc][64][32]
    #pragma unroll
    for (int i=0;i<5;i++){
      int idx = tid*8 + i*4096;
      int kc = idx >> 11;           // /2048
      int rem = idx & 2047;
      int n = rem >> 5, k8 = rem & 31;
      g2l16(W1Tl + (long)(n1_0 + n)*320 + kc*32 + k8, Ws + idx);
    }
    __syncthreads();
    // u-phase: wave computes u rows wave*16..+16, cols 0..63 (4 tiles)
    float4v uacc[4];
    #pragma unroll
    for (int j=0;j<4;j++) uacc[j] = (float4v){0.f,0.f,0.f,0.f};
    #pragma unroll
    for (int kc=0; kc<10; ++kc){
      half8 bw[4];
      #pragma unroll
      for (int j=0;j<4;j++) bw[j] = *(const half8*)&Ws[kc*2048 + (j*16+r)*32 + q*8];
      #pragma unroll
      for (int j=0;j<4;j++)
        uacc[j] = __builtin_amdgcn_mfma_f32_16x16x32_f16(aReg[kc], bw[j], uacc[j], 0,0,0);
    }
    // bias + relu + write u to LDS [kc2][row][32]
    #pragma unroll
    for (int j=0;j<4;j++){
      int nloc = j*16 + r;
      int n1g = n1_0 + nloc;
      float bv = (n1g < 600) ? h2f(b1l[n1g]) : 0.f;
      int kc2 = nloc >> 5, c32 = nloc & 31;
      #pragma unroll
      for (int t=0;t<4;t++){
        int row = wave*16 + q*4 + t;
        float v = fmaxf(uacc[j][t] + bv, 0.f);
        uS[kc2*4096 + row*32 + c32] = f2h(v);
      }
    }
    __syncthreads();   // u visible; W1 tile reads done
    // stage W2 tile: cols n1_0..+63 of W2T (384 rows) -> [kc2][384][32]
    #pragma unroll
    for (int i=0;i<6;i++){
      int idx = tid*8 + i*4096;
      int kc2 = idx / 12288;
      int rem = idx - kc2*12288;
      int n2 = rem >> 5, k8 = rem & 31;
      g2l16(W2Tl + (long)n2*640 + n1_0 + kc2*32 + k8, Ws + idx);
    }
    __syncthreads();
    // z-phase: 4x6 tiles per wave, K = 64 (2 chunks)
    #pragma unroll
    for (int kc2=0; kc2<2; ++kc2){
      half8 af[4], bf[6];
      #pragma unroll
      for (int i=0;i<4;i++) af[i] = *(const half8*)&uS[kc2*4096 + (wr*64+i*16+r)*32 + q*8];
      #pragma unroll
      for (int j=0;j<6;j++) bf[j] = *(const half8*)&Ws[kc2*12288 + (wc*96+j*16+r)*32 + q*8];
      #pragma unroll
      for (int i=0;i<4;i++)
        #pragma unroll
        for (int j=0;j<6;j++)
          zacc[i][j] = __builtin_amdgcn_mfma_f32_16x16x32_f16(af[i], bf[j], zacc[i][j], 0,0,0);
    }
  }
  // epilogue: bias + fp16 store (cols<320) + BN stats (rows<NN)
  #pragma unroll
  for (int j=0;j<6;j++){
    int c = wc*96 + j*16 + r;
    float bv = (c < 300) ? h2f(b2l[c]) : 0.f;
    float s1 = 0.f, s2 = 0.f;
    #pragma unroll
    for (int i=0;i<4;i++){
      int rowb = m0 + wr*64 + i*16 + q*4;
      #pragma unroll
      for (int t=0;t<4;t++){
        float v = zacc[i][j][t] + bv;
        int gr = rowb + t;
        if (c < 320) Z[(long)gr*320 + c] = f2h(v);
        if (gr < NN){ s1 += v; s2 += v*v; }
      }
    }
    s1 += __shfl_xor(s1,16); s1 += __shfl_xor(s1,32);
    s2 += __shfl_xor(s2,16); s2 += __shfl_xor(s2,32);
    if (q == 0 && c < 384){ atomicAdd(&colsum[c], s1); atomicAdd(&colsumsq[c], s2); }
  }
}

// ---------------- MFMA GEMM (fp16): tail projectors + logits --------------------
// omode: 2 = fp16 out, 1 = bf16 out, 0 = fp32 out
__global__ __launch_bounds__(256) void gemm_nt(
    const u16* __restrict__ A, int lda,
    const u16* __restrict__ BT, int ldb,
    int Kp,
    const u16* __restrict__ bias, int Nreal,
    float scale, int dorelu, int omode, int Ncap,
    void* __restrict__ Cv, int ldc,
    const int* __restrict__ outmode)
{
  __shared__ __align__(16) u16 As[128*32];
  __shared__ __align__(16) u16 Bs[128*32];
  int tid = threadIdx.x;
  int wave = tid>>6, lane = tid&63;
  int wr = (wave>>1)&1, wc = wave&1;
  int m0 = blockIdx.x*128, n0 = blockIdx.y*128;
  int q = lane>>4, r = lane&15;
  int srow = tid>>2, scol = (tid&3)*8;
  const u16* Ag0 = A  + (long)(m0+srow)*lda + scol;
  const u16* Ag1 = A  + (long)(m0+64+srow)*lda + scol;
  const u16* Bg0 = BT + (long)(n0+srow)*ldb + scol;
  const u16* Bg1 = BT + (long)(n0+64+srow)*ldb + scol;
  u16* Asl0 = &As[tid*8];
  u16* Asl1 = &As[64*32 + tid*8];
  u16* Bsl0 = &Bs[tid*8];
  u16* Bsl1 = &Bs[64*32 + tid*8];
  float4v acc[4][4];
  #pragma unroll
  for (int i=0;i<4;i++)
    #pragma unroll
    for (int j=0;j<4;j++) acc[i][j] = (float4v){0.f,0.f,0.f,0.f};

  for (int k0=0; k0<Kp; k0+=32){
    g2l16(Ag0+k0, Asl0);
    g2l16(Ag1+k0, Asl1);
    g2l16(Bg0+k0, Bsl0);
    g2l16(Bg1+k0, Bsl1);
    __syncthreads();
    half8 af[4], bf[4];
    #pragma unroll
    for (int i=0;i<4;i++) af[i] = *(const half8*)&As[(wr*64+i*16+r)*32 + q*8];
    #pragma unroll
    for (int j=0;j<4;j++) bf[j] = *(const half8*)&Bs[(wc*64+j*16+r)*32 + q*8];
    #pragma unroll
    for (int i=0;i<4;i++)
      #pragma unroll
      for (int j=0;j<4;j++)
        acc[i][j] = __builtin_amdgcn_mfma_f32_16x16x32_f16(af[i], bf[j], acc[i][j], 0,0,0);
    __syncthreads();
  }

  int ob = omode;
  if (outmode) ob = (*outmode) ? 0 : 1;   // fp32 inputs -> fp32 logits, else bf16
  u16* Ch = (u16*)Cv; float* Cf = (float*)Cv;
  #pragma unroll
  for (int j=0;j<4;j++){
    int c = n0 + wc*64 + j*16 + r;
    float bv = (bias && c < Nreal) ? h2f(bias[c]) : 0.f;
    #pragma unroll
    for (int i=0;i<4;i++){
      int rowb = m0 + wr*64 + i*16 + q*4;
      #pragma unroll
      for (int tt=0; tt<4; ++tt){
        float v = acc[i][j][tt] + bv;
        if (dorelu) v = fmaxf(v, 0.f);
        v *= scale;
        int gr = rowb + tt;
        if (c < Ncap){
          long o = (long)gr*ldc + c;
          if (ob == 2)      Ch[o] = f2h(v);
          else if (ob == 1) Ch[o] = f2b(v);
          else              Cf[o] = v;
        }
      }
    }
  }
}

// ---------------- batchnorm ----------------
__global__ __launch_bounds__(320) void bn_finalize(const float* __restrict__ st, const u16* __restrict__ g,
                                                   const u16* __restrict__ b, float* __restrict__ sc,
                                                   float* __restrict__ sh){
  int c = threadIdx.x;
  if (c >= 300) return;
  float mu  = st[c] * (1.0f/NN);
  float var = st[384+c] * (1.0f/NN) - mu*mu;
  float inv = rsqrtf(var + 1e-5f);
  float gg = h2f(g[c]) * inv;
  sc[c] = gg; sh[c] = h2f(b[c]) - mu*gg;
}
__global__ __launch_bounds__(256) void bn_apply(const u16* __restrict__ z, const float* __restrict__ sc,
                                                const float* __restrict__ sh, u16* __restrict__ h, int dorelu){
  int idx = blockIdx.x*256 + threadIdx.x;
  if (idx >= NN*150) return;
  int n = idx/150, p = idx - n*150;
  ushort2 zz = ((const ushort2*)z)[n*160 + p];
  int d = 2*p;
  float v0 = h2f(zz.x)*sc[d  ] + sh[d  ];
  float v1 = h2f(zz.y)*sc[d+1] + sh[d+1];
  if (dorelu){ v0 = fmaxf(v0,0.f); v1 = fmaxf(v1,0.f); }
  ((ushort2*)h)[n*160 + p] = make_ushort2(f2h(v0), f2h(v1));
}

// ---------------- pooling / branch tail ----------------
__global__ __launch_bounds__(256) void graph_starts(const int* __restrict__ ids, int* __restrict__ starts){
  int i = blockIdx.x*256 + threadIdx.x;
  if (i >= NN) return;
  int b = ids[i];
  if (i == 0){ for (int g=0; g<=b; ++g) starts[g] = 0; }
  else { int p = ids[i-1]; for (int g=p+1; g<=b; ++g) starts[g] = i; }
  if (i == NN-1){ for (int g=b+1; g<=NG; ++g) starts[g] = NN; }
}
__global__ __launch_bounds__(256) void pool_kernel(const u16* __restrict__ h, const int* __restrict__ starts,
                                                   u16* __restrict__ pooled){
  int g = blockIdx.x*4 + (threadIdx.x>>6);
  int lane = threadIdx.x & 63;
  if (g >= NG) return;
  int s = starts[g], e = starts[g+1];
  int cnt = e - s; if (cnt < 1) cnt = 1;
  float inv = 1.0f/(float)cnt;
  float ax[3] = {0,0,0}, ay[3] = {0,0,0};
  const ushort2* h2 = (const ushort2*)h;
  for (int row=s; row<e; ++row){
    long base = (long)row*160;
    #pragma unroll
    for (int jp=0; jp<3; ++jp){
      int p = jp*64 + lane;
      if (p < 160){ ushort2 v = h2[base+p]; ax[jp] += h2f(v.x); ay[jp] += h2f(v.y); }
    }
  }
  ushort2* o2 = (ushort2*)pooled;
  #pragma unroll
  for (int jp=0; jp<3; ++jp){
    int p = jp*64 + lane;
    if (p < 160) o2[g*160+p] = make_ushort2(f2h(ax[jp]*inv), f2h(ay[jp]*inv));
  }
}
__global__ __launch_bounds__(256) void gather_rows(const u16* __restrict__ h, const int* __restrict__ idxs,
                                                   u16* __restrict__ out){
  int idx = blockIdx.x*256 + threadIdx.x;
  if (idx >= NG*160) return;
  int g = idx/160, p = idx - g*160;
  ((ushort2*)out)[idx] = ((const ushort2*)h)[(long)idxs[g]*160 + p];
}
__global__ __launch_bounds__(256) void add_norm(const float* __restrict__ vp, const float* __restrict__ vd,
                                                u16* __restrict__ f){
  int g = blockIdx.x*4 + (threadIdx.x>>6);
  int lane = threadIdx.x & 63;
  if (g >= NG) return;
  float vals[5]; float ss = 0.f;
  #pragma unroll
  for (int t=0; t<5; ++t){
    int d = lane + 64*t; float v = 0.f;
    if (d < 300) v = vp[g*320+d] + vd[g*320+d];
    vals[t] = v; ss += v*v;
  }
  #pragma unroll
  for (int off=32; off>0; off>>=1) ss += __shfl_xor(ss, off);
  float inv = rsqrtf(ss);
  #pragma unroll
  for (int t=0; t<5; ++t){
    int d = lane + 64*t;
    if (d < 320) f[g*320+d] = f2h(d < 300 ? vals[t]*inv : 0.f);
  }
}

// ---------------- host orchestration ----------------
extern "C" void kernel_launch(void* const* d_in, const int* in_sizes, int n_in,
                              void* d_out, int out_size, void* d_ws, size_t ws_size,
                              hipStream_t stream)
{
  const int* xin[2]  = {(const int*)d_in[0], (const int*)d_in[5]};
  const int* ei[2]   = {(const int*)d_in[1], (const int*)d_in[6]};
  const int* ea[2]   = {(const int*)d_in[2], (const int*)d_in[7]};
  const int* bid[2]  = {(const int*)d_in[3], (const int*)d_in[8]};
  const int* dang[2] = {(const int*)d_in[4], (const int*)d_in[9]};
  (void)in_sizes; (void)n_in; (void)out_size; (void)ws_size;

  char* w = (char*)d_ws;
  auto alloc = [&](size_t bytes)->char* {
    char* p = w; w += (bytes + 255) & ~(size_t)255; return p;
  };
  // big buffers (z aliases agg: block reads its own A rows before writing them)
  u16* hA   = (u16*)alloc((size_t)MPAD*320*2);   // 64.06 MB
  u16* agg  = (u16*)alloc((size_t)MPAD*320*2);   // 64.06 MB (also "z")
  u16* z    = agg;
  // tail buffers
  u16*   pooled = (u16*)alloc((size_t)NG*320*2);
  u16*   hd     = (u16*)alloc((size_t)NG*320*2);
  u16*   ubuf   = (u16*)alloc((size_t)NG*384*2);
  float* vpb    = (float*)alloc((size_t)NG*320*4);
  float* vdb    = (float*)alloc((size_t)NG*320*4);
  // small buffers
  u16* ec   = (u16*)alloc((size_t)LL*18*320*2);
  u16* W1T  = (u16*)alloc((size_t)LL*640*320*2);
  u16* W2T  = (u16*)alloc((size_t)LL*384*640*2);
  u16* pW1T = (u16*)alloc((size_t)4*384*320*2);
  u16* pW2T = (u16*)alloc((size_t)4*384*384*2);
  int* counts = (int*)alloc((size_t)NN*4);
  int* cursor = (int*)alloc((size_t)NN*4);
  int* offs   = (int*)alloc((size_t)(NN+1)*4);
  int* perm   = (int*)alloc((size_t)NE*4);
  int* csums  = (int*)alloc(512);
  int* cbase  = (int*)alloc(512);
  float* stats = (float*)alloc(768*4);
  float* bnsc  = (float*)alloc(384*4);
  float* bnsh  = (float*)alloc(384*4);
  int* starts  = (int*)alloc((size_t)(NG+1)*4);
  u16* f0b     = (u16*)alloc((size_t)NG*320*2);
  u16* f1b     = (u16*)alloc((size_t)NG*320*2);
  int* dflag   = (int*)alloc(256);
  // fp16 param arena
  const int pcnt[14] = {36000, 900, 9000, 4500, 900000, 3000, 900000, 1500,
                        1500, 1500, 360000, 1200, 360000, 1200};
  u16* parena = (u16*)alloc((size_t)2580300*2 + 14*256);
  u16* pp[14];
  { size_t off = 0;
    for (int i=0;i<14;i++){ pp[i] = parena + off; off += (size_t)((pcnt[i]+127)&~127); } }
  u16* ae1 = pp[0];  u16* ae2 = pp[1];  u16* ee1 = pp[2];  u16* ee2 = pp[3];
  u16* W1  = pp[4];  u16* b1  = pp[5];  u16* W2  = pp[6];  u16* b2  = pp[7];
  u16* bng = pp[8];  u16* bnb = pp[9];  u16* pW1 = pp[10]; u16* pb1 = pp[11];
  u16* pW2 = pp[12]; u16* pb2 = pp[13];

  auto cdiv = [](long a, long b){ return (int)((a + b - 1)/b); };
  auto gemm = [&](const u16* A, int lda, const u16* BT, int ldb, int Kp,
                  const u16* bias, int Nreal, float scale, int relu, int omode, int Ncap,
                  void* C, int ldc, int gx, int gy, const int* om){
    gemm_nt<<<dim3(gx,gy), 256, 0, stream>>>(A,lda,BT,ldb,Kp,bias,Nreal,scale,relu,omode,Ncap,
                                             C,ldc,om);
  };

  // ---- dtype probe + param normalization ----
  zero32<<<1,256,0,stream>>>((unsigned*)dflag, 1);
  detect_dtype<<<16,256,0,stream>>>((const u16*)d_in[14], dflag);
  for (int i=0;i<14;i++)
    cvt_param<<<cdiv(pcnt[i],256),256,0,stream>>>(d_in[10+i], pp[i], pcnt[i], dflag);

  // weight prep
  tpad<<<cdiv((long)LL*640*320,256),256,0,stream>>>(W1,  W1T,  LL, 300, 600, 320, 640);
  tpad<<<cdiv((long)LL*384*640,256),256,0,stream>>>(W2,  W2T,  LL, 600, 300, 640, 384);
  tpad<<<cdiv((long)4*384*320,256),256,0,stream>>>(pW1, pW1T, 4,  300, 300, 320, 384);
  tpad<<<cdiv((long)4*384*384,256),256,0,stream>>>(pW2, pW2T, 4,  300, 300, 384, 384);
  ecomb_build<<<cdiv((long)LL*18*160,256),256,0,stream>>>(ee1, ee2, ec);

  for (int br=0; br<2; ++br){
    u16* fo = br ? f1b : f0b;
    node_init<<<cdiv((long)MPAD*160,256),256,0,stream>>>(xin[br], ae1, ae2, hA);
    // CSR by dst
    zero32<<<cdiv(NN,256),256,0,stream>>>((unsigned*)counts, NN);
    hist<<<cdiv(NE,256),256,0,stream>>>(ei[br], counts);
    scan_chunks<<<NCHUNK,256,0,stream>>>(counts, csums);
    scan_base<<<1,128,0,stream>>>(csums, cbase, offs);
    scan_final<<<NCHUNK,256,0,stream>>>(counts, cbase, offs);
    zero32<<<cdiv(NN,256),256,0,stream>>>((unsigned*)cursor, NN);
    fill_perm<<<cdiv(NE,256),256,0,stream>>>(ei[br], ea[br], offs, cursor, perm);

    for (int l=0; l<LL; ++l){
      aggregate<<<MPAD/4,256,0,stream>>>(hA, ec + (size_t)l*18*320, offs, perm, agg);
      zero32<<<3,256,0,stream>>>((unsigned*)stats, 768);
      gin_mlp<<<MPAD/128, 512, 0, stream>>>(agg,
          W1T + (size_t)l*640*320, b1 + l*600,
          W2T + (size_t)l*384*640, b2 + l*300,
          z, stats, stats+384);
      bn_finalize<<<1,320,0,stream>>>(stats, bng + l*300, bnb + l*300, bnsc, bnsh);
      bn_apply<<<cdiv((long)NN*150,256),256,0,stream>>>(z, bnsc, bnsh, hA, (l < LL-1) ? 1 : 0);
    }

    graph_starts<<<cdiv(NN,256),256,0,stream>>>(bid[br], starts);
    pool_kernel<<<NG/4,256,0,stream>>>(hA, starts, pooled);
    gather_rows<<<cdiv((long)NG*160,256),256,0,stream>>>(hA, dang[br], hd);

    int pi = br, dpi = 2 + br;
    gemm(pooled, 320, pW1T + (size_t)pi*384*320, 320, 320,
         pb1 + pi*300, 300, 1.f, 1, 2, 384, ubuf, 384, NG/128, 3, nullptr);
    gemm(ubuf, 384, pW2T + (size_t)pi*384*384, 384, 384,
         pb2 + pi*300, 300, 1.f, 0, 0, 320, vpb, 320, NG/128, 3, nullptr);
    gemm(hd, 320, pW1T + (size_t)dpi*384*320, 320, 320,
         pb1 + dpi*300, 300, 1.f, 1, 2, 384, ubuf, 384, NG/128, 3, nullptr);
    gemm(ubuf, 384, pW2T + (size_t)dpi*384*384, 384, 384,
         pb2 + dpi*300, 300, 1.f, 0, 0, 320, vdb, 320, NG/128, 3, nullptr);
    add_norm<<<NG/4,256,0,stream>>>(vpb, vdb, fo);
  }

  // logits = (f0 @ f1^T) / 0.04 -> dtype per detected mode (fp32 here)
  gemm(f0b, 320, f1b, 320, 320, nullptr, 0, 25.0f, 0, 1, NG,
       d_out, NG, NG/128, NG/128, dflag);
}

// Round 7
// 3706.388 us; speedup vs baseline: 1.3150x; 1.0828x over previous
//
#include <hip/hip_runtime.h>

// ---------------- constants ----------------
#define NN    100000      // nodes per batch
#define NE    400000      // edges per batch
#define NG    4096        // graphs
#define LL    5
#define MPAD  100096      // 782*128
#define NCHUNK 98         // ceil(NN/1024)

typedef unsigned short u16;
typedef __attribute__((ext_vector_type(8))) _Float16 half8;
typedef __attribute__((ext_vector_type(4))) _Float16 hv4;
typedef __attribute__((ext_vector_type(4))) float float4v;
typedef __attribute__((ext_vector_type(16))) float float16v;

// bf16 decode/encode (for dtype probe + bf16-output fallback)
__device__ __forceinline__ float b2f(u16 u){
  union { float f; unsigned u; } c; c.u = ((unsigned)u)<<16; return c.f;
}
__device__ __forceinline__ u16 f2b(float f){
  union { float f; unsigned u; } c; c.f = f;
  unsigned x = c.u;
  return (u16)((x + 0x7fffu + ((x>>16)&1u)) >> 16);
}
// fp16 decode/encode (pipeline precision)
__device__ __forceinline__ float h2f(u16 u){
  union { u16 s; _Float16 h; } c; c.s = u; return (float)c.h;
}
__device__ __forceinline__ u16 f2h(float f){
  union { u16 s; _Float16 h; } c; c.h = (_Float16)f; return c.s;
}
__device__ __forceinline__ void g2l16(const u16* g, u16* l){
  __builtin_amdgcn_global_load_lds((const __attribute__((address_space(1))) void*)g,
                                   (__attribute__((address_space(3))) void*)l, 16, 0, 0);
}

// ---------------- dtype detection / normalization ----------------
__global__ __launch_bounds__(256) void detect_dtype(const u16* __restrict__ p, int* __restrict__ flag){
  int i = blockIdx.x*256 + threadIdx.x;   // 16 blocks -> 4096 halves
  float v = b2f(p[i]);
  if (!(fabsf(v) <= 1e4f)) atomicOr(flag, 1);
}
__global__ __launch_bounds__(256) void cvt_param(const void* __restrict__ src, u16* __restrict__ dst,
                                                 int n, const int* __restrict__ flag){
  int i = blockIdx.x*256 + threadIdx.x;
  if (i >= n) return;
  float v = (*flag) ? ((const float*)src)[i] : b2f(((const u16*)src)[i]);
  dst[i] = f2h(v);
}

// ---------------- small utility kernels ----------------
__global__ __launch_bounds__(256) void zero32(unsigned* __restrict__ p, int n){
  int i = blockIdx.x*256 + threadIdx.x;
  if (i < n) p[i] = 0u;
}

// transpose+pad: dst[l][n][k] = src[l][k][n], zero outside (fp16 elements)
__global__ __launch_bounds__(256) void tpad(const u16* __restrict__ src, u16* __restrict__ dst,
                                            int L, int K, int N, int Kp, int Np){
  int idx = blockIdx.x*256 + threadIdx.x;
  if (idx >= L*Np*Kp) return;
  int l = idx/(Np*Kp); int r = idx - l*Np*Kp; int n = r/Kp; int k = r - n*Kp;
  dst[idx] = (n<N && k<K) ? src[(l*K + k)*N + n] : (u16)0;
}

// ecomb[l][c][0:320] = eemb1[l][c/3] + eemb2[l][c%3], cols>=300 zero. fp16.
__global__ __launch_bounds__(256) void ecomb_build(const u16* __restrict__ ee1, const u16* __restrict__ ee2,
                                                   u16* __restrict__ ec){
  int idx = blockIdx.x*256 + threadIdx.x;
  if (idx >= LL*18*160) return;
  int l = idx/(18*160); int r = idx - l*18*160; int c = r/160; int p = r - c*160;
  int a0 = c/3, a1 = c - a0*3;
  u16 o0=0,o1=0;
  if (p < 150){
    int d = 2*p;
    o0 = f2h(h2f(ee1[(l*6+a0)*300+d  ]) + h2f(ee2[(l*3+a1)*300+d  ]));
    o1 = f2h(h2f(ee1[(l*6+a0)*300+d+1]) + h2f(ee2[(l*3+a1)*300+d+1]));
  }
  ((ushort2*)ec)[idx] = make_ushort2(o0,o1);
}

// h[n][0:320] = atom_emb1[x[n,0]] + atom_emb2[x[n,1]]; pads zero (fp16)
__global__ __launch_bounds__(256) void node_init(const int* __restrict__ x, const u16* __restrict__ ae1,
                                                 const u16* __restrict__ ae2, u16* __restrict__ h){
  int idx = blockIdx.x*256 + threadIdx.x;
  if (idx >= MPAD*160) return;
  int n = idx/160, p = idx - n*160;
  u16 o0=0,o1=0;
  if (n < NN && p < 150){
    int a = x[2*n], ch = x[2*n+1];
    int d = 2*p;
    o0 = f2h(h2f(ae1[a*300+d  ]) + h2f(ae2[ch*300+d  ]));
    o1 = f2h(h2f(ae1[a*300+d+1]) + h2f(ae2[ch*300+d+1]));
  }
  ((ushort2*)h)[idx] = make_ushort2(o0,o1);
}

// ---------------- CSR build ----------------
__global__ __launch_bounds__(256) void hist(const int* __restrict__ ei, int* __restrict__ counts){
  int e = blockIdx.x*256 + threadIdx.x;
  if (e >= NE) return;
  atomicAdd(&counts[ei[NE + e]], 1);
}
__global__ __launch_bounds__(256) void scan_chunks(const int* __restrict__ counts, int* __restrict__ csums){
  __shared__ int sd[256];
  int base = blockIdx.x*1024;
  int s = 0;
  for (int i = threadIdx.x; i < 1024; i += 256){ int g = base+i; if (g < NN) s += counts[g]; }
  sd[threadIdx.x] = s; __syncthreads();
  for (int off=128; off>0; off>>=1){ if (threadIdx.x < off) sd[threadIdx.x] += sd[threadIdx.x+off]; __syncthreads(); }
  if (threadIdx.x == 0) csums[blockIdx.x] = sd[0];
}
__global__ __launch_bounds__(128) void scan_base(const int* __restrict__ csums, int* __restrict__ cbase,
                                                 int* __restrict__ offsets){
  __shared__ int sd[128];
  int tid = threadIdx.x;
  int v = (tid < NCHUNK) ? csums[tid] : 0;
  sd[tid] = v; __syncthreads();
  for (int off=1; off<128; off<<=1){
    int t = (tid >= off) ? sd[tid-off] : 0; __syncthreads();
    sd[tid] += t; __syncthreads();
  }
  if (tid < NCHUNK) cbase[tid] = sd[tid] - v;
  if (tid == 0) offsets[NN] = sd[NCHUNK-1];
}
__global__ __launch_bounds__(256) void scan_final(const int* __restrict__ counts, const int* __restrict__ cbase,
                                                  int* __restrict__ offsets){
  __shared__ int sd[256];
  int tid = threadIdx.x;
  int base = blockIdx.x*1024 + tid*4;
  int v0 = (base   < NN) ? counts[base  ] : 0;
  int v1 = (base+1 < NN) ? counts[base+1] : 0;
  int v2 = (base+2 < NN) ? counts[base+2] : 0;
  int v3 = (base+3 < NN) ? counts[base+3] : 0;
  int s = v0+v1+v2+v3;
  sd[tid] = s; __syncthreads();
  for (int off=1; off<256; off<<=1){
    int t = (tid >= off) ? sd[tid-off] : 0; __syncthreads();
    sd[tid] += t; __syncthreads();
  }
  int run = cbase[blockIdx.x] + sd[tid] - s;
  if (base   < NN){ offsets[base  ] = run; } run += v0;
  if (base+1 < NN){ offsets[base+1] = run; } run += v1;
  if (base+2 < NN){ offsets[base+2] = run; } run += v2;
  if (base+3 < NN){ offsets[base+3] = run; }
}
// pack src*32+combo so aggregate needs ONE load per edge
__global__ __launch_bounds__(256) void fill_perm(const int* __restrict__ ei, const int* __restrict__ ea,
                                                 const int* __restrict__ offsets,
                                                 int* __restrict__ cursor, int* __restrict__ pk){
  int e = blockIdx.x*256 + threadIdx.x;
  if (e >= NE) return;
  int d = ei[NE + e];
  int src = ei[e];
  int c = ea[2*e]*3 + ea[2*e+1];
  int pos = offsets[d] + atomicAdd(&cursor[d], 1);
  pk[pos] = src*32 + c;
}

// ---------------- aggregation (wave/node, packed fp16 adds, 4-edge unroll) ------
__global__ __launch_bounds__(256) void aggregate(
    const u16* __restrict__ h, const u16* __restrict__ ecL,
    const int* __restrict__ offsets, const int* __restrict__ pk,
    u16* __restrict__ agg)
{
  __shared__ u16 ecs[18*320];
  for (int i = threadIdx.x; i < 18*160; i += 256)
    ((ushort2*)ecs)[i] = ((const ushort2*)ecL)[i];
  __syncthreads();
  int node = blockIdx.x*4 + (threadIdx.x>>6);
  int lane = threadIdx.x & 63;
  bool tl = lane < 16;
  const hv4* h4 = (const hv4*)h;
  const hv4* e4 = (const hv4*)ecs;
  long base = (long)node*80;
  hv4 acc0, acc1 = (hv4)(_Float16)0;
  // self: h + ec[12] (bond 4, dir 0)
  acc0 = h4[base + lane] + e4[12*80 + lane];
  if (tl) acc1 = h4[base + 64 + lane] + e4[12*80 + 64 + lane];
  if (node < NN){
    int s = offsets[node], en = offsets[node+1];
    int i = s;
    while (i + 3 < en){
      int p0 = pk[i], p1 = pk[i+1], p2 = pk[i+2], p3 = pk[i+3]; i += 4;
      long b0 = (long)(p0>>5)*80, b1 = (long)(p1>>5)*80;
      long b2 = (long)(p2>>5)*80, b3 = (long)(p3>>5)*80;
      int c0 = (p0&31)*80, c1 = (p1&31)*80, c2 = (p2&31)*80, c3 = (p3&31)*80;
      hv4 a0 = h4[b0+lane], a1 = h4[b1+lane], a2 = h4[b2+lane], a3 = h4[b3+lane];
      hv4 e0 = e4[c0+lane], e1 = e4[c1+lane], e2 = e4[c2+lane], e3 = e4[c3+lane];
      acc0 += (a0+e0); acc0 += (a1+e1); acc0 += (a2+e2); acc0 += (a3+e3);
      if (tl){
        hv4 x0 = h4[b0+64+lane], x1 = h4[b1+64+lane];
        hv4 x2 = h4[b2+64+lane], x3 = h4[b3+64+lane];
        hv4 y0 = e4[c0+64+lane], y1 = e4[c1+64+lane];
        hv4 y2 = e4[c2+64+lane], y3 = e4[c3+64+lane];
        acc1 += (x0+y0); acc1 += (x1+y1); acc1 += (x2+y2); acc1 += (x3+y3);
      }
    }
    while (i < en){
      int p0 = pk[i]; ++i;
      long b0 = (long)(p0>>5)*80; int c0 = (p0&31)*80;
      acc0 += (h4[b0+lane] + e4[c0+lane]);
      if (tl) acc1 += (h4[b0+64+lane] + e4[c0+64+lane]);
    }
  }
  hv4* a4 = (hv4*)agg;
  a4[base + lane] = acc0;
  if (tl) a4[base + 64 + lane] = acc1;
}

// ---------------- FUSED GIN MLP v2: z = relu(A*W1+b1)*W2+b2 + BN stats ----------
// 512 thr / 128 rows. u-phase: 32x32x16 MFMA, A in regs (32 rows per lane-group).
// z-phase: 16x16x32 (verified layout). LDS = uS 16KB + W-region 48KB = 64KB exact.
// W1 tile [64][328] (pad 8 -> stride 164 dw === 4 mod 32, conflict-free staged reads).
__global__ __launch_bounds__(512, 2) void gin_mlp(
    const u16* __restrict__ A,        // [MPAD][320]
    const u16* __restrict__ W1Tl,     // [640][320]
    const u16* __restrict__ b1l,      // [600]
    const u16* __restrict__ W2Tl,     // [384][640]
    const u16* __restrict__ b2l,      // [300]
    u16* __restrict__ Z,              // [MPAD][320]
    float* __restrict__ colsum, float* __restrict__ colsumsq)
{
  __shared__ __align__(16) u16 lds[32768];   // 64 KB
  u16* uS = lds;           // [2][128][32] = 8192 u16
  u16* Ws = lds + 8192;    // W1 [64][328]=20992 u16  |  W2 [2][384][32]=24576 u16
  int tid = threadIdx.x;
  int wave = tid>>6, lane = tid&63;
  int n5 = lane & 31, hi = lane >> 5;   // 32x32 ids
  int q = lane>>4, r = lane&15;         // 16x16 ids
  int rg = wave>>1, ch = wave&1;        // u-phase: rows rg*32, col-half ch
  int wr = wave>>2, wc = wave&3;        // z-phase: rows wr*64, cols wc*96
  int m0 = blockIdx.x*128;

  // A rows into registers (32x32 A-layout: m=n5, k=kc*16+hi*8)
  half8 aReg[20];
  const u16* Arow = A + (long)(m0 + rg*32 + n5)*320 + hi*8;
  #pragma unroll
  for (int kc=0; kc<20; ++kc) aReg[kc] = *(const half8*)(Arow + kc*16);

  float4v zacc[4][6];
  #pragma unroll
  for (int i=0;i<4;i++)
    #pragma unroll
    for (int j=0;j<6;j++) zacc[i][j] = (float4v){0.f,0.f,0.f,0.f};

  for (int t1=0; t1<10; ++t1){
    int n1_0 = t1*64;
    __syncthreads();   // prior z-phase done with uS/Ws
    // stage W1 tile [64 n][328 k] (20992 u16 = 2624 16B-chunks, 41 chunks/row)
    #pragma unroll
    for (int rnd=0; rnd<5; ++rnd){
      int ck = rnd*512 + tid;
      int n = ck/41, k8 = ck - n*41;
      const u16* src = (k8 < 40) ? (W1Tl + (long)(n1_0 + n)*320 + k8*8) : W1Tl;
      g2l16(src, Ws + ck*8);
    }
    if (tid < 64){
      int ck = 2560 + tid;
      int n = ck/41, k8 = ck - n*41;
      const u16* src = (k8 < 40) ? (W1Tl + (long)(n1_0 + n)*320 + k8*8) : W1Tl;
      g2l16(src, Ws + ck*8);
    }
    __syncthreads();
    // u-phase: wave computes u[rg*32..+31][ch*32..+31] via 32x32x16
    float16v uacc = (float16v)(0.f);
    #pragma unroll
    for (int kc=0; kc<20; ++kc){
      half8 bw = *(const half8*)&Ws[(ch*32 + n5)*328 + kc*16 + hi*8];
      uacc = __builtin_amdgcn_mfma_f32_32x32x16_f16(aReg[kc], bw, uacc, 0,0,0);
    }
    // bias + relu + write u to uS[ch][row][32] (col = n5)
    {
      int n1g = n1_0 + ch*32 + n5;
      float bv = (n1g < 600) ? h2f(b1l[n1g]) : 0.f;
      u16* uw = uS + ch*4096 + n5;
      #pragma unroll
      for (int reg=0; reg<16; ++reg){
        int row = rg*32 + (reg&3) + 8*(reg>>2) + 4*hi;
        float v = fmaxf(uacc[reg] + bv, 0.f);
        uw[row*32] = f2h(v);
      }
    }
    __syncthreads();   // u visible; W1 reads done
    // stage W2 tile [2 kc2][384 n][32 k]
    #pragma unroll
    for (int i=0;i<6;i++){
      int idx = tid*8 + i*4096;
      int kc2 = idx / 12288;
      int rem = idx - kc2*12288;
      int n2 = rem >> 5, k8 = rem & 31;
      g2l16(W2Tl + (long)n2*640 + n1_0 + kc2*32 + k8, Ws + idx);
    }
    __syncthreads();
    // z-phase: 16x16x32, K = 64 (2 chunks)
    #pragma unroll
    for (int kc2=0; kc2<2; ++kc2){
      half8 af[4], bf[6];
      #pragma unroll
      for (int i=0;i<4;i++) af[i] = *(const half8*)&uS[kc2*4096 + (wr*64+i*16+r)*32 + q*8];
      #pragma unroll
      for (int j=0;j<6;j++) bf[j] = *(const half8*)&Ws[kc2*12288 + (wc*96+j*16+r)*32 + q*8];
      #pragma unroll
      for (int i=0;i<4;i++)
        #pragma unroll
        for (int j=0;j<6;j++)
          zacc[i][j] = __builtin_amdgcn_mfma_f32_16x16x32_f16(af[i], bf[j], zacc[i][j], 0,0,0);
    }
  }
  // epilogue: bias + fp16 store (cols<320) + BN stats (rows<NN)
  #pragma unroll
  for (int j=0;j<6;j++){
    int c = wc*96 + j*16 + r;
    float bv = (c < 300) ? h2f(b2l[c]) : 0.f;
    float s1 = 0.f, s2 = 0.f;
    #pragma unroll
    for (int i=0;i<4;i++){
      int rowb = m0 + wr*64 + i*16 + q*4;
      #pragma unroll
      for (int t=0;t<4;t++){
        float v = zacc[i][j][t] + bv;
        int gr = rowb + t;
        if (c < 320) Z[(long)gr*320 + c] = f2h(v);
        if (gr < NN){ s1 += v; s2 += v*v; }
      }
    }
    s1 += __shfl_xor(s1,16); s1 += __shfl_xor(s1,32);
    s2 += __shfl_xor(s2,16); s2 += __shfl_xor(s2,32);
    if (q == 0 && c < 384){ atomicAdd(&colsum[c], s1); atomicAdd(&colsumsq[c], s2); }
  }
}

// ---------------- MFMA GEMM (fp16): tail projectors + logits --------------------
// omode: 2 = fp16 out, 1 = bf16 out, 0 = fp32 out
__global__ __launch_bounds__(256) void gemm_nt(
    const u16* __restrict__ A, int lda,
    const u16* __restrict__ BT, int ldb,
    int Kp,
    const u16* __restrict__ bias, int Nreal,
    float scale, int dorelu, int omode, int Ncap,
    void* __restrict__ Cv, int ldc,
    const int* __restrict__ outmode)
{
  __shared__ __align__(16) u16 As[128*32];
  __shared__ __align__(16) u16 Bs[128*32];
  int tid = threadIdx.x;
  int wave = tid>>6, lane = tid&63;
  int wr = (wave>>1)&1, wc = wave&1;
  int m0 = blockIdx.x*128, n0 = blockIdx.y*128;
  int q = lane>>4, r = lane&15;
  int srow = tid>>2, scol = (tid&3)*8;
  const u16* Ag0 = A  + (long)(m0+srow)*lda + scol;
  const u16* Ag1 = A  + (long)(m0+64+srow)*lda + scol;
  const u16* Bg0 = BT + (long)(n0+srow)*ldb + scol;
  const u16* Bg1 = BT + (long)(n0+64+srow)*ldb + scol;
  u16* Asl0 = &As[tid*8];
  u16* Asl1 = &As[64*32 + tid*8];
  u16* Bsl0 = &Bs[tid*8];
  u16* Bsl1 = &Bs[64*32 + tid*8];
  float4v acc[4][4];
  #pragma unroll
  for (int i=0;i<4;i++)
    #pragma unroll
    for (int j=0;j<4;j++) acc[i][j] = (float4v){0.f,0.f,0.f,0.f};

  for (int k0=0; k0<Kp; k0+=32){
    g2l16(Ag0+k0, Asl0);
    g2l16(Ag1+k0, Asl1);
    g2l16(Bg0+k0, Bsl0);
    g2l16(Bg1+k0, Bsl1);
    __syncthreads();
    half8 af[4], bf[4];
    #pragma unroll
    for (int i=0;i<4;i++) af[i] = *(const half8*)&As[(wr*64+i*16+r)*32 + q*8];
    #pragma unroll
    for (int j=0;j<4;j++) bf[j] = *(const half8*)&Bs[(wc*64+j*16+r)*32 + q*8];
    #pragma unroll
    for (int i=0;i<4;i++)
      #pragma unroll
      for (int j=0;j<4;j++)
        acc[i][j] = __builtin_amdgcn_mfma_f32_16x16x32_f16(af[i], bf[j], acc[i][j], 0,0,0);
    __syncthreads();
  }

  int ob = omode;
  if (outmode) ob = (*outmode) ? 0 : 1;   // fp32 inputs -> fp32 logits, else bf16
  u16* Ch = (u16*)Cv; float* Cf = (float*)Cv;
  #pragma unroll
  for (int j=0;j<4;j++){
    int c = n0 + wc*64 + j*16 + r;
    float bv = (bias && c < Nreal) ? h2f(bias[c]) : 0.f;
    #pragma unroll
    for (int i=0;i<4;i++){
      int rowb = m0 + wr*64 + i*16 + q*4;
      #pragma unroll
      for (int tt=0; tt<4; ++tt){
        float v = acc[i][j][tt] + bv;
        if (dorelu) v = fmaxf(v, 0.f);
        v *= scale;
        int gr = rowb + tt;
        if (c < Ncap){
          long o = (long)gr*ldc + c;
          if (ob == 2)      Ch[o] = f2h(v);
          else if (ob == 1) Ch[o] = f2b(v);
          else              Cf[o] = v;
        }
      }
    }
  }
}

// ---------------- batchnorm ----------------
__global__ __launch_bounds__(320) void bn_finalize(const float* __restrict__ st, const u16* __restrict__ g,
                                                   const u16* __restrict__ b, float* __restrict__ sc,
                                                   float* __restrict__ sh){
  int c = threadIdx.x;
  if (c >= 300) return;
  float mu  = st[c] * (1.0f/NN);
  float var = st[384+c] * (1.0f/NN) - mu*mu;
  float inv = rsqrtf(var + 1e-5f);
  float gg = h2f(g[c]) * inv;
  sc[c] = gg; sh[c] = h2f(b[c]) - mu*gg;
}
__global__ __launch_bounds__(256) void bn_apply(const u16* __restrict__ z, const float* __restrict__ sc,
                                                const float* __restrict__ sh, u16* __restrict__ h, int dorelu){
  int idx = blockIdx.x*256 + threadIdx.x;
  if (idx >= NN*150) return;
  int n = idx/150, p = idx - n*150;
  ushort2 zz = ((const ushort2*)z)[n*160 + p];
  int d = 2*p;
  float v0 = h2f(zz.x)*sc[d  ] + sh[d  ];
  float v1 = h2f(zz.y)*sc[d+1] + sh[d+1];
  if (dorelu){ v0 = fmaxf(v0,0.f); v1 = fmaxf(v1,0.f); }
  ((ushort2*)h)[n*160 + p] = make_ushort2(f2h(v0), f2h(v1));
}

// ---------------- pooling / branch tail ----------------
__global__ __launch_bounds__(256) void graph_starts(const int* __restrict__ ids, int* __restrict__ starts){
  int i = blockIdx.x*256 + threadIdx.x;
  if (i >= NN) return;
  int b = ids[i];
  if (i == 0){ for (int g=0; g<=b; ++g) starts[g] = 0; }
  else { int p = ids[i-1]; for (int g=p+1; g<=b; ++g) starts[g] = i; }
  if (i == NN-1){ for (int g=b+1; g<=NG; ++g) starts[g] = NN; }
}
__global__ __launch_bounds__(256) void pool_kernel(const u16* __restrict__ h, const int* __restrict__ starts,
                                                   u16* __restrict__ pooled){
  int g = blockIdx.x*4 + (threadIdx.x>>6);
  int lane = threadIdx.x & 63;
  if (g >= NG) return;
  int s = starts[g], e = starts[g+1];
  int cnt = e - s; if (cnt < 1) cnt = 1;
  float inv = 1.0f/(float)cnt;
  float ax[3] = {0,0,0}, ay[3] = {0,0,0};
  const ushort2* h2 = (const ushort2*)h;
  for (int row=s; row<e; ++row){
    long base = (long)row*160;
    #pragma unroll
    for (int jp=0; jp<3; ++jp){
      int p = jp*64 + lane;
      if (p < 160){ ushort2 v = h2[base+p]; ax[jp] += h2f(v.x); ay[jp] += h2f(v.y); }
    }
  }
  ushort2* o2 = (ushort2*)pooled;
  #pragma unroll
  for (int jp=0; jp<3; ++jp){
    int p = jp*64 + lane;
    if (p < 160) o2[g*160+p] = make_ushort2(f2h(ax[jp]*inv), f2h(ay[jp]*inv));
  }
}
__global__ __launch_bounds__(256) void gather_rows(const u16* __restrict__ h, const int* __restrict__ idxs,
                                                   u16* __restrict__ out){
  int idx = blockIdx.x*256 + threadIdx.x;
  if (idx >= NG*160) return;
  int g = idx/160, p = idx - g*160;
  ((ushort2*)out)[idx] = ((const ushort2*)h)[(long)idxs[g]*160 + p];
}
__global__ __launch_bounds__(256) void add_norm(const float* __restrict__ vp, const float* __restrict__ vd,
                                                u16* __restrict__ f){
  int g = blockIdx.x*4 + (threadIdx.x>>6);
  int lane = threadIdx.x & 63;
  if (g >= NG) return;
  float vals[5]; float ss = 0.f;
  #pragma unroll
  for (int t=0; t<5; ++t){
    int d = lane + 64*t; float v = 0.f;
    if (d < 300) v = vp[g*320+d] + vd[g*320+d];
    vals[t] = v; ss += v*v;
  }
  #pragma unroll
  for (int off=32; off>0; off>>=1) ss += __shfl_xor(ss, off);
  float inv = rsqrtf(ss);
  #pragma unroll
  for (int t=0; t<5; ++t){
    int d = lane + 64*t;
    if (d < 320) f[g*320+d] = f2h(d < 300 ? vals[t]*inv : 0.f);
  }
}

// ---------------- host orchestration ----------------
extern "C" void kernel_launch(void* const* d_in, const int* in_sizes, int n_in,
                              void* d_out, int out_size, void* d_ws, size_t ws_size,
                              hipStream_t stream)
{
  const int* xin[2]  = {(const int*)d_in[0], (const int*)d_in[5]};
  const int* ei[2]   = {(const int*)d_in[1], (const int*)d_in[6]};
  const int* ea[2]   = {(const int*)d_in[2], (const int*)d_in[7]};
  const int* bid[2]  = {(const int*)d_in[3], (const int*)d_in[8]};
  const int* dang[2] = {(const int*)d_in[4], (const int*)d_in[9]};
  (void)in_sizes; (void)n_in; (void)out_size; (void)ws_size;

  char* w = (char*)d_ws;
  auto alloc = [&](size_t bytes)->char* {
    char* p = w; w += (bytes + 255) & ~(size_t)255; return p;
  };
  // big buffers (z aliases agg: block reads its own A rows before writing them)
  u16* hA   = (u16*)alloc((size_t)MPAD*320*2);   // 64.06 MB
  u16* agg  = (u16*)alloc((size_t)MPAD*320*2);   // 64.06 MB (also "z")
  u16* z    = agg;
  // tail buffers
  u16*   pooled = (u16*)alloc((size_t)NG*320*2);
  u16*   hd     = (u16*)alloc((size_t)NG*320*2);
  u16*   ubuf   = (u16*)alloc((size_t)NG*384*2);
  float* vpb    = (float*)alloc((size_t)NG*320*4);
  float* vdb    = (float*)alloc((size_t)NG*320*4);
  // small buffers
  u16* ec   = (u16*)alloc((size_t)LL*18*320*2);
  u16* W1T  = (u16*)alloc((size_t)LL*640*320*2);
  u16* W2T  = (u16*)alloc((size_t)LL*384*640*2);
  u16* pW1T = (u16*)alloc((size_t)4*384*320*2);
  u16* pW2T = (u16*)alloc((size_t)4*384*384*2);
  int* counts = (int*)alloc((size_t)NN*4);
  int* cursor = (int*)alloc((size_t)NN*4);
  int* offs   = (int*)alloc((size_t)(NN+1)*4);
  int* perm   = (int*)alloc((size_t)NE*4);
  int* csums  = (int*)alloc(512);
  int* cbase  = (int*)alloc(512);
  float* stats = (float*)alloc(768*4);
  float* bnsc  = (float*)alloc(384*4);
  float* bnsh  = (float*)alloc(384*4);
  int* starts  = (int*)alloc((size_t)(NG+1)*4);
  u16* f0b     = (u16*)alloc((size_t)NG*320*2);
  u16* f1b     = (u16*)alloc((size_t)NG*320*2);
  int* dflag   = (int*)alloc(256);
  // fp16 param arena
  const int pcnt[14] = {36000, 900, 9000, 4500, 900000, 3000, 900000, 1500,
                        1500, 1500, 360000, 1200, 360000, 1200};
  u16* parena = (u16*)alloc((size_t)2580300*2 + 14*256);
  u16* pp[14];
  { size_t off = 0;
    for (int i=0;i<14;i++){ pp[i] = parena + off; off += (size_t)((pcnt[i]+127)&~127); } }
  u16* ae1 = pp[0];  u16* ae2 = pp[1];  u16* ee1 = pp[2];  u16* ee2 = pp[3];
  u16* W1  = pp[4];  u16* b1  = pp[5];  u16* W2  = pp[6];  u16* b2  = pp[7];
  u16* bng = pp[8];  u16* bnb = pp[9];  u16* pW1 = pp[10]; u16* pb1 = pp[11];
  u16* pW2 = pp[12]; u16* pb2 = pp[13];

  auto cdiv = [](long a, long b){ return (int)((a + b - 1)/b); };
  auto gemm = [&](const u16* A, int lda, const u16* BT, int ldb, int Kp,
                  const u16* bias, int Nreal, float scale, int relu, int omode, int Ncap,
                  void* C, int ldc, int gx, int gy, const int* om){
    gemm_nt<<<dim3(gx,gy), 256, 0, stream>>>(A,lda,BT,ldb,Kp,bias,Nreal,scale,relu,omode,Ncap,
                                             C,ldc,om);
  };

  // ---- dtype probe + param normalization ----
  zero32<<<1,256,0,stream>>>((unsigned*)dflag, 1);
  detect_dtype<<<16,256,0,stream>>>((const u16*)d_in[14], dflag);
  for (int i=0;i<14;i++)
    cvt_param<<<cdiv(pcnt[i],256),256,0,stream>>>(d_in[10+i], pp[i], pcnt[i], dflag);

  // weight prep
  tpad<<<cdiv((long)LL*640*320,256),256,0,stream>>>(W1,  W1T,  LL, 300, 600, 320, 640);
  tpad<<<cdiv((long)LL*384*640,256),256,0,stream>>>(W2,  W2T,  LL, 600, 300, 640, 384);
  tpad<<<cdiv((long)4*384*320,256),256,0,stream>>>(pW1, pW1T, 4,  300, 300, 320, 384);
  tpad<<<cdiv((long)4*384*384,256),256,0,stream>>>(pW2, pW2T, 4,  300, 300, 384, 384);
  ecomb_build<<<cdiv((long)LL*18*160,256),256,0,stream>>>(ee1, ee2, ec);

  for (int br=0; br<2; ++br){
    u16* fo = br ? f1b : f0b;
    node_init<<<cdiv((long)MPAD*160,256),256,0,stream>>>(xin[br], ae1, ae2, hA);
    // CSR by dst
    zero32<<<cdiv(NN,256),256,0,stream>>>((unsigned*)counts, NN);
    hist<<<cdiv(NE,256),256,0,stream>>>(ei[br], counts);
    scan_chunks<<<NCHUNK,256,0,stream>>>(counts, csums);
    scan_base<<<1,128,0,stream>>>(csums, cbase, offs);
    scan_final<<<NCHUNK,256,0,stream>>>(counts, cbase, offs);
    zero32<<<cdiv(NN,256),256,0,stream>>>((unsigned*)cursor, NN);
    fill_perm<<<cdiv(NE,256),256,0,stream>>>(ei[br], ea[br], offs, cursor, perm);

    for (int l=0; l<LL; ++l){
      aggregate<<<MPAD/4,256,0,stream>>>(hA, ec + (size_t)l*18*320, offs, perm, agg);
      zero32<<<3,256,0,stream>>>((unsigned*)stats, 768);
      gin_mlp<<<MPAD/128, 512, 0, stream>>>(agg,
          W1T + (size_t)l*640*320, b1 + l*600,
          W2T + (size_t)l*384*640, b2 + l*300,
          z, stats, stats+384);
      bn_finalize<<<1,320,0,stream>>>(stats, bng + l*300, bnb + l*300, bnsc, bnsh);
      bn_apply<<<cdiv((long)NN*150,256),256,0,stream>>>(z, bnsc, bnsh, hA, (l < LL-1) ? 1 : 0);
    }

    graph_starts<<<cdiv(NN,256),256,0,stream>>>(bid[br], starts);
    pool_kernel<<<NG/4,256,0,stream>>>(hA, starts, pooled);
    gather_rows<<<cdiv((long)NG*160,256),256,0,stream>>>(hA, dang[br], hd);

    int pi = br, dpi = 2 + br;
    gemm(pooled, 320, pW1T + (size_t)pi*384*320, 320, 320,
         pb1 + pi*300, 300, 1.f, 1, 2, 384, ubuf, 384, NG/128, 3, nullptr);
    gemm(ubuf, 384, pW2T + (size_t)pi*384*384, 384, 384,
         pb2 + pi*300, 300, 1.f, 0, 0, 320, vpb, 320, NG/128, 3, nullptr);
    gemm(hd, 320, pW1T + (size_t)dpi*384*320, 320, 320,
         pb1 + dpi*300, 300, 1.f, 1, 2, 384, ubuf, 384, NG/128, 3, nullptr);
    gemm(ubuf, 384, pW2T + (size_t)dpi*384*384, 384, 384,
         pb2 + dpi*300, 300, 1.f, 0, 0, 320, vdb, 320, NG/128, 3, nullptr);
    add_norm<<<NG/4,256,0,stream>>>(vpb, vdb, fo);
  }

  // logits = (f0 @ f1^T) / 0.04 -> dtype per detected mode (fp32 here)
  gemm(f0b, 320, f1b, 320, 320, nullptr, 0, 25.0f, 0, 1, NG,
       d_out, NG, NG/128, NG/128, dflag);
}